// Round 13
// baseline (826.389 us; speedup 1.0000x reference)
//
#include <hip/hip_runtime.h>
#include <cstdint>
#include <cstddef>

#define N_NODES 20000
#define N_PAD   20096   // 157*128
#define N_EDGES 640000
#define DDIM    256
#define HIDD    512
#define NBLK    6
#define HEXP    2048    // HID*EXP
#define NCLS    3
#define RNK     512
#define NGENE   6640
#define NGPAD   6656    // 26*256
#define NBATCH  4096

typedef __attribute__((ext_vector_type(8))) short short8;
typedef __attribute__((ext_vector_type(4))) float f32x4;

__device__ __forceinline__ float gelu_tanh(float x) {
    float x3 = x * x * x;
    return 0.5f * x * (1.f + tanhf(0.7978845608028654f * (x + 0.044715f * x3)));
}

// f32 -> bf16 RNE bit pattern
__device__ __forceinline__ unsigned short f2bf(float f) {
    unsigned u = __float_as_uint(f);
    unsigned r = (u + 0x7FFFu + ((u >> 16) & 1u)) >> 16;
    return (unsigned short)r;
}

__device__ __forceinline__ float bf2f(unsigned short h) {
    return __uint_as_float((unsigned)h << 16);
}

// async global->LDS, 16B per lane. LDS dest is wave-uniform base + lane*16.
__device__ __forceinline__ void gload16(const unsigned short* g, short* l) {
    __builtin_amdgcn_global_load_lds(
        (const __attribute__((address_space(1))) void*)g,
        (__attribute__((address_space(3))) void*)l, 16, 0, 0);
}

// counted vmcnt wait (immediate must be literal)
template <int N>
__device__ __forceinline__ void waitvm() {
    if constexpr (N == 0)      asm volatile("s_waitcnt vmcnt(0)" ::: "memory");
    else if constexpr (N == 6) asm volatile("s_waitcnt vmcnt(6)" ::: "memory");
    else if constexpr (N == 8) asm volatile("s_waitcnt vmcnt(8)" ::: "memory");
    else if constexpr (N == 12) asm volatile("s_waitcnt vmcnt(12)" ::: "memory");
    else static_assert(N == 0, "unsupported vmcnt");
}

// block remap: XCD-bijective chunking (m204) + 16-row supertiles for L2 reuse.
__device__ __forceinline__ void remap_block(int& bx, int& by) {
    const int NBX = gridDim.x, NBY = gridDim.y;
    const int nwg = NBX * NBY;
    int orig = blockIdx.y * NBX + blockIdx.x;
    int q = nwg >> 3, r = nwg & 7;
    int xcd = orig & 7, lid = orig >> 3;
    int w = (xcd < r ? xcd * (q + 1) : r * (q + 1) + (xcd - r) * q) + lid;
    int G = NBY < 16 ? NBY : 16;
    int per = G * NBX;
    int full = NBY / G;
    if (w < full * per) {
        int g = w / per, rem = w % per;
        bx = rem / G;
        by = g * G + (rem % G);
    } else {
        int w2 = w - full * per;
        int tG = NBY - full * G;
        bx = w2 / tG;
        by = full * G + w2 % tG;
    }
}

// ---------------- utility kernels ----------------
// merged: initX + gene f32->bf16 convert + gathered-node marking
__global__ __launch_bounds__(256) void init_and_gene_kernel(const float4* __restrict__ fro,
                                                            float4* __restrict__ X,
                                                            ushort4* __restrict__ Xb, int n4x,
                                                            const float* __restrict__ gene,
                                                            unsigned short* __restrict__ geneB,
                                                            int n4g,
                                                            const int* __restrict__ idxs,
                                                            int* __restrict__ mark) {
    int i = blockIdx.x * 256 + threadIdx.x;
    if (i < n4x) {
        float4 v = fro[i];
        X[i] = v;
        ushort4 h;
        h.x = f2bf(v.x); h.y = f2bf(v.y); h.z = f2bf(v.z); h.w = f2bf(v.w);
        Xb[i] = h;
    } else if (i < n4x + n4g) {
        int j = i - n4x;
        float4 v = ((const float4*)gene)[j];
        ushort4 o;
        o.x = f2bf(v.x); o.y = f2bf(v.y); o.z = f2bf(v.z); o.w = f2bf(v.w);
        ((ushort4*)geneB)[j] = o;
    } else {
        int b = i - n4x - n4g;
        if (b < NBATCH) {
            int id = idxs[b];
            mark[id < 0 ? 0 : id] = 1;   // benign race: all write 1
        }
    }
}

// ---------------- fused weight prep (+ cnt/mark zeroing tail blocks) ----------------
#define PREP_TILES 13376
#define ZERO_BLKS  ((N_NODES + 255) / 256)   // 79
__global__ __launch_bounds__(256) void prep_all_kernel(
        const float* W6, const float* W7, const float* Wp, const float* inW,
        const float* f1W, const float* f2W, const float* oW,
        unsigned short* W6T, unsigned short* W7T, unsigned short* WpT, unsigned short* inWT,
        unsigned short* f1WT, unsigned short* f2WT, unsigned short* oWT,
        int* cnt, int* mark) {
    int id = blockIdx.x;
    if (id >= PREP_TILES) {           // tail blocks: zero CSR histogram + mark flags
        int z = id - PREP_TILES;
        if (z < ZERO_BLKS) {
            int i = z * 256 + threadIdx.x;
            if (i < N_NODES) cnt[i] = 0;
        } else {
            int i = (z - ZERO_BLKS) * 256 + threadIdx.x;
            if (i < N_NODES) mark[i] = 0;
        }
        return;
    }
    const float* in; unsigned short* out; int R, C, nx, local;
    if (id < 192) {            // W6/W7/Wp
        int m = id / 64; local = id % 64;
        in = m == 0 ? W6 : (m == 1 ? W7 : Wp);
        out = m == 0 ? W6T : (m == 1 ? W7T : WpT);
        R = DDIM; C = DDIM; nx = 8;
    } else if (id < 320) {     // inW 256x512
        local = id - 192; in = inW; out = inWT; R = DDIM; C = HIDD; nx = 16;
    } else if (id < 6464) {    // f1W 6 x 512x2048
        local = id - 320; int layer = local / 1024; local %= 1024;
        in = f1W + (size_t)layer * HIDD * HEXP; out = f1WT + (size_t)layer * HEXP * HIDD;
        R = HIDD; C = HEXP; nx = 64;
    } else if (id < 12608) {   // f2W 6 x 2048x512
        local = id - 6464; int layer = local / 1024; local %= 1024;
        in = f2W + (size_t)layer * HEXP * HIDD; out = f2WT + (size_t)layer * HIDD * HEXP;
        R = HEXP; C = HIDD; nx = 16;
    } else {                   // oW 512x1536
        local = id - 12608; in = oW; out = oWT; R = HIDD; C = NCLS * RNK; nx = 48;
    }
    int bx = local % nx, by = local / nx;
    __shared__ float tile[32][33];
    int c0 = bx * 32, r0 = by * 32;
    int tx = threadIdx.x & 31, ty = threadIdx.x >> 5;
#pragma unroll
    for (int i = 0; i < 4; ++i) {
        int r = r0 + ty + i * 8, c = c0 + tx;
        tile[ty + i * 8][tx] = (r < R && c < C) ? in[(size_t)r * C + c] : 0.f;
    }
    __syncthreads();
#pragma unroll
    for (int i = 0; i < 4; ++i) {
        int c = c0 + ty + i * 8, r = r0 + tx;
        if (c < C && r < R) out[(size_t)c * R + r] = f2bf(tile[tx][ty + i * 8]);
    }
}

// ---------------- CSR build ----------------
__global__ __launch_bounds__(256) void hist_kernel(const int* __restrict__ dst,
                                                   int* __restrict__ cnt) {
    int e = blockIdx.x * 256 + threadIdx.x;
    if (e < N_EDGES) atomicAdd(&cnt[dst[e]], 1);
}

__global__ __launch_bounds__(256) void scan_kernel(const int* __restrict__ cnt,
                                                   int* __restrict__ off,
                                                   int* __restrict__ cur) {
    __shared__ int part[256];
    const int CH = (N_NODES + 255) / 256;
    int t = threadIdx.x;
    int base = t * CH;
    int s = 0;
    for (int j = 0; j < CH; ++j) {
        int i = base + j;
        if (i < N_NODES) s += cnt[i];
    }
    part[t] = s;
    __syncthreads();
    for (int d = 1; d < 256; d <<= 1) {
        int v = (t >= d) ? part[t - d] : 0;
        __syncthreads();
        part[t] += v;
        __syncthreads();
    }
    int run = part[t] - s;
    for (int j = 0; j < CH; ++j) {
        int i = base + j;
        if (i < N_NODES) {
            off[i] = run; cur[i] = run;
            run += cnt[i];
        }
    }
    if (t == 255) off[N_NODES] = run;
}

__global__ __launch_bounds__(256) void fill_kernel(const int* __restrict__ src,
                                                   const int* __restrict__ dst,
                                                   const float* __restrict__ ew,
                                                   int* __restrict__ cur,
                                                   int* __restrict__ ssrc,
                                                   float* __restrict__ sw) {
    int e = blockIdx.x * 256 + threadIdx.x;
    if (e >= N_EDGES) return;
    int slot = atomicAdd(&cur[dst[e]], 1);
    ssrc[slot] = src[e];
    sw[slot]   = ew[e];
}

// fused aggregation + update, one wave per node, bf16 Y rows, 4-deep unrolled.
// mark != nullptr: only process marked nodes (layer-2: only gathered nodes are read)
template <bool WB>
__global__ __launch_bounds__(256) void agg_update_kernel(const unsigned short* __restrict__ Y,
                                                         const int* __restrict__ off,
                                                         const int* __restrict__ ssrc,
                                                         const float* __restrict__ sw,
                                                         const float* __restrict__ bias,
                                                         float* __restrict__ X,
                                                         unsigned short* __restrict__ Xb,
                                                         const int* __restrict__ mark) {
    int node = blockIdx.x * 4 + (threadIdx.x >> 6);
    int lane = threadIdx.x & 63;
    if (mark != nullptr && mark[node] == 0) return;   // wave-uniform
    int b = off[node], e = off[node + 1];
    const ushort4* Yv = (const ushort4*)Y;
    float4 acc = make_float4(0.f, 0.f, 0.f, 0.f);
    int j = b;
    for (; j + 3 < e; j += 4) {
        int s0 = ssrc[j], s1 = ssrc[j + 1], s2 = ssrc[j + 2], s3 = ssrc[j + 3];
        float w0 = sw[j], w1 = sw[j + 1], w2 = sw[j + 2], w3 = sw[j + 3];
        ushort4 v0 = Yv[(size_t)s0 * 64 + lane];
        ushort4 v1 = Yv[(size_t)s1 * 64 + lane];
        ushort4 v2 = Yv[(size_t)s2 * 64 + lane];
        ushort4 v3 = Yv[(size_t)s3 * 64 + lane];
        acc.x += bf2f(v0.x) * w0 + bf2f(v1.x) * w1 + bf2f(v2.x) * w2 + bf2f(v3.x) * w3;
        acc.y += bf2f(v0.y) * w0 + bf2f(v1.y) * w1 + bf2f(v2.y) * w2 + bf2f(v3.y) * w3;
        acc.z += bf2f(v0.z) * w0 + bf2f(v1.z) * w1 + bf2f(v2.z) * w2 + bf2f(v3.z) * w3;
        acc.w += bf2f(v0.w) * w0 + bf2f(v1.w) * w1 + bf2f(v2.w) * w2 + bf2f(v3.w) * w3;
    }
    for (; j < e; ++j) {
        int s = ssrc[j];
        float w = sw[j];
        ushort4 v = Yv[(size_t)s * 64 + lane];
        acc.x += bf2f(v.x) * w; acc.y += bf2f(v.y) * w;
        acc.z += bf2f(v.z) * w; acc.w += bf2f(v.w) * w;
    }
    float4 bv = ((const float4*)bias)[lane];
    size_t o = (size_t)node * 64 + lane;
    float4 x = ((float4*)X)[o];
    x.x += fmaxf(acc.x + bv.x, 0.f);
    x.y += fmaxf(acc.y + bv.y, 0.f);
    x.z += fmaxf(acc.z + bv.z, 0.f);
    x.w += fmaxf(acc.w + bv.w, 0.f);
    ((float4*)X)[o] = x;
    if (WB) {
        ushort4 h;
        h.x = f2bf(x.x); h.y = f2bf(x.y); h.z = f2bf(x.z); h.w = f2bf(x.w);
        ((ushort4*)Xb)[o] = h;
    }
}

// gather rows of X (f32) at clip(idx,0) -> bf16 [NBATCH][DDIM]
__global__ __launch_bounds__(256) void gather_cvt_kernel(const float* __restrict__ X,
                                                         const int* __restrict__ idxs,
                                                         unsigned short* __restrict__ Ag) {
    int b = blockIdx.x, t = threadIdx.x;
    int id = idxs[b];
    if (id < 0) id = 0;
    Ag[(size_t)b * DDIM + t] = f2bf(X[(size_t)id * DDIM + t]);
}

// LN over 256 cols with OOV row substitution, bf16 out. one block per row.
__global__ __launch_bounds__(256) void ln_oov_kernel(const float* __restrict__ Z,
                                                     const int* __restrict__ idxs,
                                                     const float* __restrict__ oov,
                                                     const float* __restrict__ g,
                                                     const float* __restrict__ bb,
                                                     unsigned short* __restrict__ Y) {
    __shared__ float s1[256];
    __shared__ float s2[256];
    int row = blockIdx.x, t = threadIdx.x;
    int id = idxs[row];
    float v = (id >= 0) ? Z[(size_t)row * DDIM + t] : oov[t];
    s1[t] = v; s2[t] = v * v;
    __syncthreads();
    for (int o = 128; o > 0; o >>= 1) {
        if (t < o) { s1[t] += s1[t + o]; s2[t] += s2[t + o]; }
        __syncthreads();
    }
    float mu  = s1[0] * (1.f / DDIM);
    float var = s2[0] * (1.f / DDIM) - mu * mu;
    float r   = rsqrtf(var + 1e-5f);
    Y[(size_t)row * DDIM + t] = f2bf((v - mu) * r * g[t] + bb[t]);
}

// generic LN, f32 in -> bf16 out. one block per row.
__global__ __launch_bounds__(256) void ln_kernel(const float* __restrict__ X,
                                                 const float* __restrict__ g,
                                                 const float* __restrict__ bb,
                                                 unsigned short* __restrict__ Y, int ncol) {
    __shared__ float s1[256];
    __shared__ float s2[256];
    int row = blockIdx.x, t = threadIdx.x;
    const float* x = X + (size_t)row * ncol;
    float sum = 0.f, sq = 0.f;
    for (int c = t; c < ncol; c += 256) {
        float v = x[c];
        sum += v; sq += v * v;
    }
    s1[t] = sum; s2[t] = sq;
    __syncthreads();
    for (int o = 128; o > 0; o >>= 1) {
        if (t < o) { s1[t] += s1[t + o]; s2[t] += s2[t + o]; }
        __syncthreads();
    }
    float inv = 1.f / (float)ncol;
    float mu  = s1[0] * inv;
    float var = s2[0] * inv - mu * mu;
    float r   = rsqrtf(var + 1e-5f);
    unsigned short* y = Y + (size_t)row * ncol;
    for (int c = t; c < ncol; c += 256) {
        y[c] = f2bf((x[c] - mu) * r * g[c] + bb[c]);
    }
}

// ---------------- bf16 MFMA GEMM (dbuf + counted vmcnt + fine interleave) -------
// v3: R6 staging/vmcnt skeleton + per-kk barrier-fenced phases (m201/m218 pattern):
// {8 ds_read -> s_barrier -> lgkmcnt(0) -> setprio(1)+16 MFMA -> setprio(0)}.
// B1 (post-waitvm) gates tile-t staging; B_end gates next staging against this
// tile's ds_reads (each wave retires its reads at its lgkmcnt(0) before B_end).
// EPI: 0 = +bias ; 2 = gelu(+bias) ; 3 = C(f32) += (+bias).  BOUT: bf16 store.
// NTS: non-temporal C store.
template <int BM, int BN, int EPI, bool BOUT, bool NTS = false>
__global__ __launch_bounds__(256) void gemm_mfma(const unsigned short* __restrict__ A, int lda,
                                                 const unsigned short* __restrict__ BT, int ldb,
                                                 void* __restrict__ Cv, int ldc,
                                                 const float* __restrict__ bias,
                                                 int M, int N, int K) {
    constexpr int WM = BM / 2, WN = BN / 2;
    constexpr int MF = WM / 16, NF = WN / 16;
    constexpr int ROWS  = BM + BN;
    constexpr int NCALL = ROWS / 32;       // gload16 per wave per k-tile
    __shared__ __align__(16) short lds[2 * ROWS * 64];

    int bx, by;
    remap_block(bx, by);

    const int tid  = threadIdx.x;
    const int lane = tid & 63;
    const int wid  = tid >> 6;
    const int wr   = (wid >> 1) * WM;
    const int wc   = (wid & 1) * WN;
    const int fq   = lane >> 4;
    const int fr   = lane & 15;
    const int m0 = by * BM, n0 = bx * BN;

    const int srow  = lane >> 3;                   // row within 8-row chunk
    const int tslot = ((lane & 7) ^ srow) * 8;     // pre-swizzled global slot (elems)

    f32x4 acc[MF][NF] = {};

    auto stage = [&](int k0, int buf) {
        short* dst = lds + buf * (ROWS * 64);
#pragma unroll
        for (int c = 0; c < NCALL; ++c) {
            int r = c * 32 + wid * 8 + srow;       // concatenated row (A then B)
            const unsigned short* src =
                (r < BM) ? (A  + (size_t)(m0 + r) * lda      + k0 + tslot)
                         : (BT + (size_t)(n0 + r - BM) * ldb + k0 + tslot);
            gload16(src, dst + (c * 32 + wid * 8) * 64);
        }
    };

    const int nsteps = K >> 6;
    stage(0, 0);
    for (int t = 0; t < nsteps; ++t) {
        const int buf = t & 1;
        if (t + 1 < nsteps) {
            stage((t + 1) << 6, buf ^ 1);
            waitvm<NCALL>();                       // tile t done; t+1 stays in flight
        } else {
            waitvm<0>();
        }
        __builtin_amdgcn_sched_barrier(0);
        __builtin_amdgcn_s_barrier();              // B1: tile-t staging visible
        __builtin_amdgcn_sched_barrier(0);

        const short* L = lds + buf * (ROWS * 64);
#pragma unroll
        for (int kk = 0; kk < 2; ++kk) {           // barrier-fenced sub-phases
            short8 af[MF], bf[NF];
#pragma unroll
            for (int m = 0; m < MF; ++m) {
                int row = wr + m * 16 + fr;
                af[m] = *(const short8*)(L + row * 64 + ((kk * 4 + fq) ^ (row & 7)) * 8);
            }
#pragma unroll
            for (int n = 0; n < NF; ++n) {
                int row = BM + wc + n * 16 + fr;
                bf[n] = *(const short8*)(L + row * 64 + ((kk * 4 + fq) ^ (row & 7)) * 8);
            }
            __builtin_amdgcn_sched_barrier(0);
            __builtin_amdgcn_s_barrier();          // phase cluster barrier
            asm volatile("s_waitcnt lgkmcnt(0)" ::: "memory");
            __builtin_amdgcn_sched_barrier(0);     // rule #18: pin MFMA below wait
            __builtin_amdgcn_s_setprio(1);
#pragma unroll
            for (int m = 0; m < MF; ++m)
#pragma unroll
                for (int n = 0; n < NF; ++n)
                    acc[m][n] = __builtin_amdgcn_mfma_f32_16x16x32_bf16(af[m], bf[n], acc[m][n], 0, 0, 0);
            __builtin_amdgcn_s_setprio(0);
            __builtin_amdgcn_sched_barrier(0);
        }
        __builtin_amdgcn_s_barrier();              // B_end: all reads retired
        __builtin_amdgcn_sched_barrier(0);
    }

    float* Cf = (float*)Cv;
    unsigned short* Cb = (unsigned short*)Cv;
#pragma unroll
    for (int n = 0; n < NF; ++n) {
        int col = n0 + wc + n * 16 + fr;
        if (col >= N) continue;
        float bv = bias ? bias[col] : 0.f;
#pragma unroll
        for (int m = 0; m < MF; ++m) {
#pragma unroll
            for (int r = 0; r < 4; ++r) {
                int row = m0 + wr + m * 16 + fq * 4 + r;
                if (row >= M) continue;
                float v = acc[m][n][r] + bv;
                if (EPI == 2) v = gelu_tanh(v);
                size_t o = (size_t)row * ldc + col;
                if (EPI == 3) v += Cf[o];
                if (BOUT)      Cb[o] = f2bf(v);
                else if (NTS)  __builtin_nontemporal_store(v, &Cf[o]);
                else           Cf[o] = v;
            }
        }
    }
}

// ---------------- 256x256 8-wave gene GEMM (m201-style fine interleave) --------
// (R12 version — unchanged)
__global__ __launch_bounds__(512, 2) void gemm_gene(const unsigned short* __restrict__ A, int lda,
                                                    const unsigned short* __restrict__ BT, int ldb,
                                                    float* __restrict__ C, int ldc,
                                                    int M, int N, int K) {
    __shared__ __align__(16) short lds[2 * 512 * 64];   // [buf][A 256 rows | B 256 rows][64]

    int bx, by;
    remap_block(bx, by);

    const int tid  = threadIdx.x;
    const int lane = tid & 63;
    const int wid  = tid >> 6;          // 0..7
    const int wm   = wid >> 2;          // 0..1 -> row offset wm*128
    const int wn   = wid & 3;           // 0..3 -> col offset wn*64
    const int fq   = lane >> 4;
    const int fr   = lane & 15;
    const int m0 = by * 256, n0 = bx * 256;

    const int tslot = ((tid & 7) ^ ((tid >> 3) & 7)) * 8;   // pre-swizzled global slot

    f32x4 acc[8][4] = {};

    auto stage = [&](int k0, int buf) {
        short* dst = lds + buf * (512 * 64);
#pragma unroll
        for (int u = 0; u < 8; ++u) {
            int rw = u * 64 + wid * 8;              // wave-uniform base row
            int r  = rw + (lane >> 3);              // this lane's concat row
            const unsigned short* src =
                (r < 256) ? (A  + (size_t)(m0 + r) * lda       + k0 + tslot)
                          : (BT + (size_t)(n0 + r - 256) * ldb + k0 + tslot);
            gload16(src, dst + rw * 64);
        }
    };

    const int nsteps = K >> 6;
    stage(0, 0);
    for (int t = 0; t < nsteps; ++t) {
        const int buf = t & 1;
        if (t + 1 < nsteps) {
            stage((t + 1) << 6, buf ^ 1);
            waitvm<8>();                            // tile t done; t+1's 8 in flight
        } else {
            waitvm<0>();
        }
        __builtin_amdgcn_sched_barrier(0);
        __builtin_amdgcn_s_barrier();
        __builtin_amdgcn_sched_barrier(0);

        const short* L = lds + buf * (512 * 64);
#pragma unroll
        for (int q = 0; q < 4; ++q) {               // quadrant phases, barrier-fenced
            const int mb = (q >> 1) * 4, nb = (q & 1) * 2;
            short8 af[4][2], bf[2][2];
#pragma unroll
            for (int m = 0; m < 4; ++m) {
                int row = wm * 128 + (mb + m) * 16 + fr;
#pragma unroll
                for (int kk = 0; kk < 2; ++kk)
                    af[m][kk] = *(const short8*)(L + row * 64 + ((kk * 4 + fq) ^ (row & 7)) * 8);
            }
#pragma unroll
            for (int n = 0; n < 2; ++n) {
                int row = 256 + wn * 64 + (nb + n) * 16 + fr;
#pragma unroll
                for (int kk = 0; kk < 2; ++kk)
                    bf[n][kk] = *(const short8*)(L + row * 64 + ((kk * 4 + fq) ^ (row & 7)) * 8);
            }
            __builtin_amdgcn_sched_barrier(0);
            __builtin_amdgcn_s_barrier();           // cluster issue phase
            asm volatile("s_waitcnt lgkmcnt(0)" ::: "memory");
            __builtin_amdgcn_sched_barrier(0);      // rule #18: pin MFMA below the wait
            __builtin_amdgcn_s_setprio(1);
#pragma unroll
            for (int kk = 0; kk < 2; ++kk)
#pragma unroll
                for (int m = 0; m < 4; ++m)
#pragma unroll
                    for (int n = 0; n < 2; ++n)
                        acc[mb + m][nb + n] = __builtin_amdgcn_mfma_f32_16x16x32_bf16(
                            af[m][kk], bf[n][kk], acc[mb + m][nb + n], 0, 0, 0);
            __builtin_amdgcn_s_setprio(0);
            __builtin_amdgcn_sched_barrier(0);
            __builtin_amdgcn_s_barrier();           // end of MFMA phase
            __builtin_amdgcn_sched_barrier(0);
        }
    }

#pragma unroll
    for (int n = 0; n < 4; ++n) {
        int col = n0 + wn * 64 + n * 16 + fr;
        if (col >= N) continue;
#pragma unroll
        for (int m = 0; m < 8; ++m) {
#pragma unroll
            for (int r = 0; r < 4; ++r) {
                int row = m0 + wm * 128 + m * 16 + fq * 4 + r;
                if (row >= M) continue;
                __builtin_nontemporal_store(acc[m][n][r], &C[(size_t)row * ldc + col]);
            }
        }
    }
}

// ---------------- launcher ----------------
static inline char* align256(char* p) {
    return (char*)(((uintptr_t)p + 255) & ~(uintptr_t)255);
}

extern "C" void kernel_launch(void* const* d_in, const int* in_sizes, int n_in,
                              void* d_out, int out_size, void* d_ws, size_t ws_size,
                              hipStream_t stream) {
    const int*   idxs = (const int*)d_in[0];
    const float* fro  = (const float*)d_in[1];
    const int*   eidx = (const int*)d_in[2];
    const float* ew   = (const float*)d_in[3];
    const float* W6   = (const float*)d_in[4];
    const float* b6   = (const float*)d_in[5];
    const float* W7   = (const float*)d_in[6];
    const float* b7   = (const float*)d_in[7];
    const float* Wp   = (const float*)d_in[8];
    const float* bp   = (const float*)d_in[9];
    const float* oov  = (const float*)d_in[10];
    const float* in_g = (const float*)d_in[11];
    const float* in_b = (const float*)d_in[12];
    const float* inW  = (const float*)d_in[13];
    const float* inb  = (const float*)d_in[14];
    const float* bg   = (const float*)d_in[15];
    const float* bb   = (const float*)d_in[16];
    const float* f1W  = (const float*)d_in[17];
    const float* f1b  = (const float*)d_in[18];
    const float* f2W  = (const float*)d_in[19];
    const float* f2b  = (const float*)d_in[20];
    const float* og   = (const float*)d_in[21];
    const float* ob   = (const float*)d_in[22];
    const float* oW   = (const float*)d_in[23];
    const float* obia = (const float*)d_in[24];
    const float* gene = (const float*)d_in[25];
    float* out = (float*)d_out;

    // ---- workspace carve-up ----
    char* p = (char*)d_ws;
    auto alloc_f = [&](size_t n) { float* r = (float*)p; p = align256(p + n * 4); return r; };
    auto alloc_i = [&](size_t n) { int*   r = (int*)p;   p = align256(p + n * 4); return r; };
    auto alloc_h = [&](size_t n) { unsigned short* r = (unsigned short*)p; p = align256(p + n * 2); return r; };

    float* X    = alloc_f((size_t)N_NODES * DDIM);
    unsigned short* Yb = alloc_h((size_t)N_NODES * DDIM);
    int*   cnt  = alloc_i(N_NODES);
    int*   mark = alloc_i(N_NODES);
    int*   off  = alloc_i(N_NODES + 1);
    int*   cur  = alloc_i(N_NODES);
    int*   ssrc = alloc_i(N_EDGES);
    float* sw   = alloc_f(N_EDGES);
    unsigned short* Xb  = alloc_h((size_t)N_PAD * DDIM);      // padded rows for gload_lds
    unsigned short* Ag  = alloc_h((size_t)NBATCH * DDIM);
    float* Zp   = alloc_f((size_t)NBATCH * DDIM);
    unsigned short* HN256 = alloc_h((size_t)NBATCH * DDIM);
    float* H    = alloc_f((size_t)NBATCH * HIDD);
    unsigned short* HN512 = alloc_h((size_t)NBATCH * HIDD);
    unsigned short* Tb  = alloc_h((size_t)NBATCH * HEXP);
    unsigned short* PPb = alloc_h((size_t)NBATCH * NCLS * RNK);
    unsigned short* W6T  = alloc_h((size_t)DDIM * DDIM);
    unsigned short* W7T  = alloc_h((size_t)DDIM * DDIM);
    unsigned short* WpT  = alloc_h((size_t)DDIM * DDIM);
    unsigned short* inWT = alloc_h((size_t)HIDD * DDIM);
    unsigned short* f1WT = alloc_h((size_t)NBLK * HIDD * HEXP);
    unsigned short* f2WT = alloc_h((size_t)NBLK * HIDD * HEXP);
    unsigned short* oWT  = alloc_h((size_t)NCLS * RNK * HIDD);
    unsigned short* geneB= alloc_h((size_t)NGPAD * RNK);       // padded rows

    const int* esrc = eidx;
    const int* edst = eidx + N_EDGES;
    dim3 blk(256);

    // ---- weight prep (+cnt/mark zero tail) and init/gene/mark ----
    prep_all_kernel<<<dim3(PREP_TILES + 2 * ZERO_BLKS), blk, 0, stream>>>(
        W6, W7, Wp, inW, f1W, f2W, oW, W6T, W7T, WpT, inWT, f1WT, f2WT, oWT, cnt, mark);
    const int node4 = N_NODES * DDIM / 4;
    const int gene4 = NGENE * RNK / 4;
    init_and_gene_kernel<<<dim3((node4 + gene4 + NBATCH + 255) / 256), blk, 0, stream>>>(
        (const float4*)fro, (float4*)X, (ushort4*)Xb, node4, gene, geneB, gene4, idxs, mark);

    // ---- CSR build (by dst) ----
    hist_kernel<<<dim3(N_EDGES / 256), blk, 0, stream>>>(edst, cnt);
    scan_kernel<<<dim3(1), blk, 0, stream>>>(cnt, off, cur);
    fill_kernel<<<dim3(N_EDGES / 256), blk, 0, stream>>>(esrc, edst, ew, cur, ssrc, sw);

    // ---- GNN tail ----
    dim3 gnn_grid(DDIM / 128, N_PAD / 128);
    gemm_mfma<128, 128, 0, true><<<gnn_grid, blk, 0, stream>>>(
        Xb, DDIM, W6T, DDIM, Yb, DDIM, nullptr, N_NODES, DDIM, DDIM);
    agg_update_kernel<true><<<dim3(N_NODES / 4), blk, 0, stream>>>(
        Yb, off, ssrc, sw, b6, X, Xb, nullptr);
    gemm_mfma<128, 128, 0, true><<<gnn_grid, blk, 0, stream>>>(
        Xb, DDIM, W7T, DDIM, Yb, DDIM, nullptr, N_NODES, DDIM, DDIM);
    // layer 2: X is only read via gather -> update only gathered (marked) nodes
    agg_update_kernel<false><<<dim3(N_NODES / 4), blk, 0, stream>>>(
        Yb, off, ssrc, sw, b7, X, nullptr, mark);

    // project only gathered rows: Ag = bf16(X[clip(idx)]), Zp = Ag @ Wp + bp
    gather_cvt_kernel<<<dim3(NBATCH), blk, 0, stream>>>(X, idxs, Ag);
    gemm_mfma<64, 128, 0, false><<<dim3(DDIM / 128, NBATCH / 64), blk, 0, stream>>>(
        Ag, DDIM, WpT, DDIM, Zp, DDIM, bp, NBATCH, DDIM, DDIM);
    // oov-select + input LN fused
    ln_oov_kernel<<<dim3(NBATCH), blk, 0, stream>>>(Zp, idxs, oov, in_g, in_b, HN256);

    // ---- head ----
    gemm_mfma<64, 128, 0, false><<<dim3(HIDD / 128, NBATCH / 64), blk, 0, stream>>>(
        HN256, DDIM, inWT, DDIM, H, HIDD, inb, NBATCH, HIDD, DDIM);
    for (int i = 0; i < NBLK; ++i) {
        ln_kernel<<<dim3(NBATCH), blk, 0, stream>>>(H, bg + (size_t)i * HIDD,
                                                    bb + (size_t)i * HIDD, HN512, HIDD);
        gemm_mfma<128, 128, 2, true><<<dim3(HEXP / 128, NBATCH / 128), blk, 0, stream>>>(
            HN512, HIDD, f1WT + (size_t)i * HEXP * HIDD, HIDD, Tb, HEXP,
            f1b + (size_t)i * HEXP, NBATCH, HEXP, HIDD);
        gemm_mfma<64, 128, 3, false><<<dim3(HIDD / 128, NBATCH / 64), blk, 0, stream>>>(
            Tb, HEXP, f2WT + (size_t)i * HIDD * HEXP, HEXP, H, HIDD,
            f2b + (size_t)i * HIDD, NBATCH, HIDD, HEXP);
    }
    ln_kernel<<<dim3(NBATCH), blk, 0, stream>>>(H, og, ob, HN512, HIDD);
    gemm_mfma<128, 128, 0, true><<<dim3(NCLS * RNK / 128, NBATCH / 128), blk, 0, stream>>>(
        HN512, HIDD, oWT, HIDD, PPb, NCLS * RNK, obia, NBATCH, NCLS * RNK, HIDD);

    // ---- bilinear gene head: 256x256 8-wave fine-interleaved kernel ----
    gemm_gene<<<dim3(NGPAD / 256, NBATCH * NCLS / 256), dim3(512), 0, stream>>>(
        PPb, RNK, geneB, RNK, out, NGENE, NBATCH * NCLS, NGENE, RNK);
}

// Round 14
// 811.606 us; speedup vs baseline: 1.0182x; 1.0182x over previous
//
#include <hip/hip_runtime.h>
#include <cstdint>
#include <cstddef>

#define N_NODES 20000
#define N_PAD   20096   // 157*128
#define N_EDGES 640000
#define DDIM    256
#define HIDD    512
#define NBLK    6
#define HEXP    2048    // HID*EXP
#define NCLS    3
#define RNK     512
#define NGENE   6640
#define NGPAD   6656    // 26*256
#define NBATCH  4096

typedef __attribute__((ext_vector_type(8))) short short8;
typedef __attribute__((ext_vector_type(4))) float f32x4;

__device__ __forceinline__ float gelu_tanh(float x) {
    float x3 = x * x * x;
    return 0.5f * x * (1.f + tanhf(0.7978845608028654f * (x + 0.044715f * x3)));
}

// f32 -> bf16 RNE bit pattern
__device__ __forceinline__ unsigned short f2bf(float f) {
    unsigned u = __float_as_uint(f);
    unsigned r = (u + 0x7FFFu + ((u >> 16) & 1u)) >> 16;
    return (unsigned short)r;
}

__device__ __forceinline__ float bf2f(unsigned short h) {
    return __uint_as_float((unsigned)h << 16);
}

// async global->LDS, 16B per lane. LDS dest is wave-uniform base + lane*16.
__device__ __forceinline__ void gload16(const unsigned short* g, short* l) {
    __builtin_amdgcn_global_load_lds(
        (const __attribute__((address_space(1))) void*)g,
        (__attribute__((address_space(3))) void*)l, 16, 0, 0);
}

// counted vmcnt wait (immediate must be literal)
template <int N>
__device__ __forceinline__ void waitvm() {
    if constexpr (N == 0)      asm volatile("s_waitcnt vmcnt(0)" ::: "memory");
    else if constexpr (N == 5) asm volatile("s_waitcnt vmcnt(5)" ::: "memory");
    else if constexpr (N == 6) asm volatile("s_waitcnt vmcnt(6)" ::: "memory");
    else if constexpr (N == 8) asm volatile("s_waitcnt vmcnt(8)" ::: "memory");
    else if constexpr (N == 12) asm volatile("s_waitcnt vmcnt(12)" ::: "memory");
    else static_assert(N == 0, "unsupported vmcnt");
}

// block remap: XCD-bijective chunking (m204) + 16-row supertiles for L2 reuse.
__device__ __forceinline__ void remap_block(int& bx, int& by) {
    const int NBX = gridDim.x, NBY = gridDim.y;
    const int nwg = NBX * NBY;
    int orig = blockIdx.y * NBX + blockIdx.x;
    int q = nwg >> 3, r = nwg & 7;
    int xcd = orig & 7, lid = orig >> 3;
    int w = (xcd < r ? xcd * (q + 1) : r * (q + 1) + (xcd - r) * q) + lid;
    int G = NBY < 16 ? NBY : 16;
    int per = G * NBX;
    int full = NBY / G;
    if (w < full * per) {
        int g = w / per, rem = w % per;
        bx = rem / G;
        by = g * G + (rem % G);
    } else {
        int w2 = w - full * per;
        int tG = NBY - full * G;
        bx = w2 / tG;
        by = full * G + w2 % tG;
    }
}

// ---------------- utility kernels ----------------
// merged: initX + gene f32->bf16 convert + gathered-node marking
__global__ __launch_bounds__(256) void init_and_gene_kernel(const float4* __restrict__ fro,
                                                            float4* __restrict__ X,
                                                            ushort4* __restrict__ Xb, int n4x,
                                                            const float* __restrict__ gene,
                                                            unsigned short* __restrict__ geneB,
                                                            int n4g,
                                                            const int* __restrict__ idxs,
                                                            int* __restrict__ mark) {
    int i = blockIdx.x * 256 + threadIdx.x;
    if (i < n4x) {
        float4 v = fro[i];
        X[i] = v;
        ushort4 h;
        h.x = f2bf(v.x); h.y = f2bf(v.y); h.z = f2bf(v.z); h.w = f2bf(v.w);
        Xb[i] = h;
    } else if (i < n4x + n4g) {
        int j = i - n4x;
        float4 v = ((const float4*)gene)[j];
        ushort4 o;
        o.x = f2bf(v.x); o.y = f2bf(v.y); o.z = f2bf(v.z); o.w = f2bf(v.w);
        ((ushort4*)geneB)[j] = o;
    } else {
        int b = i - n4x - n4g;
        if (b < NBATCH) {
            int id = idxs[b];
            mark[id < 0 ? 0 : id] = 1;   // benign race: all write 1
        }
    }
}

// ---------------- fused weight prep (+ cnt/mark zeroing tail blocks) ----------------
#define PREP_TILES 13376
#define ZERO_BLKS  ((N_NODES + 255) / 256)   // 79
__global__ __launch_bounds__(256) void prep_all_kernel(
        const float* W6, const float* W7, const float* Wp, const float* inW,
        const float* f1W, const float* f2W, const float* oW,
        unsigned short* W6T, unsigned short* W7T, unsigned short* WpT, unsigned short* inWT,
        unsigned short* f1WT, unsigned short* f2WT, unsigned short* oWT,
        int* cnt, int* mark) {
    int id = blockIdx.x;
    if (id >= PREP_TILES) {           // tail blocks: zero CSR histogram + mark flags
        int z = id - PREP_TILES;
        if (z < ZERO_BLKS) {
            int i = z * 256 + threadIdx.x;
            if (i < N_NODES) cnt[i] = 0;
        } else {
            int i = (z - ZERO_BLKS) * 256 + threadIdx.x;
            if (i < N_NODES) mark[i] = 0;
        }
        return;
    }
    const float* in; unsigned short* out; int R, C, nx, local;
    if (id < 192) {            // W6/W7/Wp
        int m = id / 64; local = id % 64;
        in = m == 0 ? W6 : (m == 1 ? W7 : Wp);
        out = m == 0 ? W6T : (m == 1 ? W7T : WpT);
        R = DDIM; C = DDIM; nx = 8;
    } else if (id < 320) {     // inW 256x512
        local = id - 192; in = inW; out = inWT; R = DDIM; C = HIDD; nx = 16;
    } else if (id < 6464) {    // f1W 6 x 512x2048
        local = id - 320; int layer = local / 1024; local %= 1024;
        in = f1W + (size_t)layer * HIDD * HEXP; out = f1WT + (size_t)layer * HEXP * HIDD;
        R = HIDD; C = HEXP; nx = 64;
    } else if (id < 12608) {   // f2W 6 x 2048x512
        local = id - 6464; int layer = local / 1024; local %= 1024;
        in = f2W + (size_t)layer * HEXP * HIDD; out = f2WT + (size_t)layer * HIDD * HEXP;
        R = HEXP; C = HIDD; nx = 16;
    } else {                   // oW 512x1536
        local = id - 12608; in = oW; out = oWT; R = HIDD; C = NCLS * RNK; nx = 48;
    }
    int bx = local % nx, by = local / nx;
    __shared__ float tile[32][33];
    int c0 = bx * 32, r0 = by * 32;
    int tx = threadIdx.x & 31, ty = threadIdx.x >> 5;
#pragma unroll
    for (int i = 0; i < 4; ++i) {
        int r = r0 + ty + i * 8, c = c0 + tx;
        tile[ty + i * 8][tx] = (r < R && c < C) ? in[(size_t)r * C + c] : 0.f;
    }
    __syncthreads();
#pragma unroll
    for (int i = 0; i < 4; ++i) {
        int c = c0 + ty + i * 8, r = r0 + tx;
        if (c < C && r < R) out[(size_t)c * R + r] = f2bf(tile[tx][ty + i * 8]);
    }
}

// ---------------- CSR build ----------------
__global__ __launch_bounds__(256) void hist_kernel(const int* __restrict__ dst,
                                                   int* __restrict__ cnt) {
    int e = blockIdx.x * 256 + threadIdx.x;
    if (e < N_EDGES) atomicAdd(&cnt[dst[e]], 1);
}

__global__ __launch_bounds__(256) void scan_kernel(const int* __restrict__ cnt,
                                                   int* __restrict__ off,
                                                   int* __restrict__ cur) {
    __shared__ int part[256];
    const int CH = (N_NODES + 255) / 256;
    int t = threadIdx.x;
    int base = t * CH;
    int s = 0;
    for (int j = 0; j < CH; ++j) {
        int i = base + j;
        if (i < N_NODES) s += cnt[i];
    }
    part[t] = s;
    __syncthreads();
    for (int d = 1; d < 256; d <<= 1) {
        int v = (t >= d) ? part[t - d] : 0;
        __syncthreads();
        part[t] += v;
        __syncthreads();
    }
    int run = part[t] - s;
    for (int j = 0; j < CH; ++j) {
        int i = base + j;
        if (i < N_NODES) {
            off[i] = run; cur[i] = run;
            run += cnt[i];
        }
    }
    if (t == 255) off[N_NODES] = run;
}

__global__ __launch_bounds__(256) void fill_kernel(const int* __restrict__ src,
                                                   const int* __restrict__ dst,
                                                   const float* __restrict__ ew,
                                                   int* __restrict__ cur,
                                                   int* __restrict__ ssrc,
                                                   float* __restrict__ sw) {
    int e = blockIdx.x * 256 + threadIdx.x;
    if (e >= N_EDGES) return;
    int slot = atomicAdd(&cur[dst[e]], 1);
    ssrc[slot] = src[e];
    sw[slot]   = ew[e];
}

// fused aggregation + update, one wave per node, bf16 Y rows, 4-deep unrolled.
// mark != nullptr: only process marked nodes (layer-2: only gathered nodes are read)
template <bool WB>
__global__ __launch_bounds__(256) void agg_update_kernel(const unsigned short* __restrict__ Y,
                                                         const int* __restrict__ off,
                                                         const int* __restrict__ ssrc,
                                                         const float* __restrict__ sw,
                                                         const float* __restrict__ bias,
                                                         float* __restrict__ X,
                                                         unsigned short* __restrict__ Xb,
                                                         const int* __restrict__ mark) {
    int node = blockIdx.x * 4 + (threadIdx.x >> 6);
    int lane = threadIdx.x & 63;
    if (mark != nullptr && mark[node] == 0) return;   // wave-uniform
    int b = off[node], e = off[node + 1];
    const ushort4* Yv = (const ushort4*)Y;
    float4 acc = make_float4(0.f, 0.f, 0.f, 0.f);
    int j = b;
    for (; j + 3 < e; j += 4) {
        int s0 = ssrc[j], s1 = ssrc[j + 1], s2 = ssrc[j + 2], s3 = ssrc[j + 3];
        float w0 = sw[j], w1 = sw[j + 1], w2 = sw[j + 2], w3 = sw[j + 3];
        ushort4 v0 = Yv[(size_t)s0 * 64 + lane];
        ushort4 v1 = Yv[(size_t)s1 * 64 + lane];
        ushort4 v2 = Yv[(size_t)s2 * 64 + lane];
        ushort4 v3 = Yv[(size_t)s3 * 64 + lane];
        acc.x += bf2f(v0.x) * w0 + bf2f(v1.x) * w1 + bf2f(v2.x) * w2 + bf2f(v3.x) * w3;
        acc.y += bf2f(v0.y) * w0 + bf2f(v1.y) * w1 + bf2f(v2.y) * w2 + bf2f(v3.y) * w3;
        acc.z += bf2f(v0.z) * w0 + bf2f(v1.z) * w1 + bf2f(v2.z) * w2 + bf2f(v3.z) * w3;
        acc.w += bf2f(v0.w) * w0 + bf2f(v1.w) * w1 + bf2f(v2.w) * w2 + bf2f(v3.w) * w3;
    }
    for (; j < e; ++j) {
        int s = ssrc[j];
        float w = sw[j];
        ushort4 v = Yv[(size_t)s * 64 + lane];
        acc.x += bf2f(v.x) * w; acc.y += bf2f(v.y) * w;
        acc.z += bf2f(v.z) * w; acc.w += bf2f(v.w) * w;
    }
    float4 bv = ((const float4*)bias)[lane];
    size_t o = (size_t)node * 64 + lane;
    float4 x = ((float4*)X)[o];
    x.x += fmaxf(acc.x + bv.x, 0.f);
    x.y += fmaxf(acc.y + bv.y, 0.f);
    x.z += fmaxf(acc.z + bv.z, 0.f);
    x.w += fmaxf(acc.w + bv.w, 0.f);
    ((float4*)X)[o] = x;
    if (WB) {
        ushort4 h;
        h.x = f2bf(x.x); h.y = f2bf(x.y); h.z = f2bf(x.z); h.w = f2bf(x.w);
        ((ushort4*)Xb)[o] = h;
    }
}

// gather rows of X (f32) at clip(idx,0) -> bf16 [NBATCH][DDIM]
__global__ __launch_bounds__(256) void gather_cvt_kernel(const float* __restrict__ X,
                                                         const int* __restrict__ idxs,
                                                         unsigned short* __restrict__ Ag) {
    int b = blockIdx.x, t = threadIdx.x;
    int id = idxs[b];
    if (id < 0) id = 0;
    Ag[(size_t)b * DDIM + t] = f2bf(X[(size_t)id * DDIM + t]);
}

// LN over 256 cols with OOV row substitution, bf16 out. one block per row.
__global__ __launch_bounds__(256) void ln_oov_kernel(const float* __restrict__ Z,
                                                     const int* __restrict__ idxs,
                                                     const float* __restrict__ oov,
                                                     const float* __restrict__ g,
                                                     const float* __restrict__ bb,
                                                     unsigned short* __restrict__ Y) {
    __shared__ float s1[256];
    __shared__ float s2[256];
    int row = blockIdx.x, t = threadIdx.x;
    int id = idxs[row];
    float v = (id >= 0) ? Z[(size_t)row * DDIM + t] : oov[t];
    s1[t] = v; s2[t] = v * v;
    __syncthreads();
    for (int o = 128; o > 0; o >>= 1) {
        if (t < o) { s1[t] += s1[t + o]; s2[t] += s2[t + o]; }
        __syncthreads();
    }
    float mu  = s1[0] * (1.f / DDIM);
    float var = s2[0] * (1.f / DDIM) - mu * mu;
    float r   = rsqrtf(var + 1e-5f);
    Y[(size_t)row * DDIM + t] = f2bf((v - mu) * r * g[t] + bb[t]);
}

// generic LN, f32 in -> bf16 out. one block per row.
__global__ __launch_bounds__(256) void ln_kernel(const float* __restrict__ X,
                                                 const float* __restrict__ g,
                                                 const float* __restrict__ bb,
                                                 unsigned short* __restrict__ Y, int ncol) {
    __shared__ float s1[256];
    __shared__ float s2[256];
    int row = blockIdx.x, t = threadIdx.x;
    const float* x = X + (size_t)row * ncol;
    float sum = 0.f, sq = 0.f;
    for (int c = t; c < ncol; c += 256) {
        float v = x[c];
        sum += v; sq += v * v;
    }
    s1[t] = sum; s2[t] = sq;
    __syncthreads();
    for (int o = 128; o > 0; o >>= 1) {
        if (t < o) { s1[t] += s1[t + o]; s2[t] += s2[t + o]; }
        __syncthreads();
    }
    float inv = 1.f / (float)ncol;
    float mu  = s1[0] * inv;
    float var = s2[0] * inv - mu * mu;
    float r   = rsqrtf(var + 1e-5f);
    unsigned short* y = Y + (size_t)row * ncol;
    for (int c = t; c < ncol; c += 256) {
        y[c] = f2bf((x[c] - mu) * r * g[c] + bb[c]);
    }
}

// ---------------- bf16 MFMA GEMM (dbuf + counted vmcnt pipeline) ----------------
// R6/R12-proven form: 256 threads = 4 waves (2x2), wave tile (BM/2)x(BN/2),
// BK=64, double-buffered LDS, counted vmcnt (never 0 mid-loop) + raw s_barrier.
// BM=32 variant (MF=1) doubles blocks/CU for N<=512 shapes (occupancy fix).
// EPI: 0 = +bias ; 2 = gelu(+bias) ; 3 = C(f32) += (+bias).  BOUT: bf16 store.
// NTS: non-temporal C store.
template <int BM, int BN, int EPI, bool BOUT, bool NTS = false>
__global__ __launch_bounds__(256) void gemm_mfma(const unsigned short* __restrict__ A, int lda,
                                                 const unsigned short* __restrict__ BT, int ldb,
                                                 void* __restrict__ Cv, int ldc,
                                                 const float* __restrict__ bias,
                                                 int M, int N, int K) {
    constexpr int WM = BM / 2, WN = BN / 2;
    constexpr int MF = WM / 16, NF = WN / 16;
    constexpr int ROWS  = BM + BN;
    constexpr int NCALL = ROWS / 32;       // gload16 per wave per k-tile
    __shared__ __align__(16) short lds[2 * ROWS * 64];

    int bx, by;
    remap_block(bx, by);

    const int tid  = threadIdx.x;
    const int lane = tid & 63;
    const int wid  = tid >> 6;
    const int wr   = (wid >> 1) * WM;
    const int wc   = (wid & 1) * WN;
    const int fq   = lane >> 4;
    const int fr   = lane & 15;
    const int m0 = by * BM, n0 = bx * BN;

    const int srow  = lane >> 3;                   // row within 8-row chunk
    const int tslot = ((lane & 7) ^ srow) * 8;     // pre-swizzled global slot (elems)

    f32x4 acc[MF][NF] = {};

    auto stage = [&](int k0, int buf) {
        short* dst = lds + buf * (ROWS * 64);
#pragma unroll
        for (int c = 0; c < NCALL; ++c) {
            int r = c * 32 + wid * 8 + srow;       // concatenated row (A then B)
            const unsigned short* src =
                (r < BM) ? (A  + (size_t)(m0 + r) * lda      + k0 + tslot)
                         : (BT + (size_t)(n0 + r - BM) * ldb + k0 + tslot);
            gload16(src, dst + (c * 32 + wid * 8) * 64);
        }
    };

    const int nsteps = K >> 6;
    stage(0, 0);
    for (int t = 0; t < nsteps; ++t) {
        const int buf = t & 1;
        if (t + 1 < nsteps) {
            stage((t + 1) << 6, buf ^ 1);
            waitvm<NCALL>();                       // tile t done; t+1 stays in flight
        } else {
            waitvm<0>();
        }
        __builtin_amdgcn_sched_barrier(0);
        __builtin_amdgcn_s_barrier();
        __builtin_amdgcn_sched_barrier(0);

        const short* L = lds + buf * (ROWS * 64);
#pragma unroll
        for (int kk = 0; kk < 2; ++kk) {
            short8 af[MF], bf[NF];
#pragma unroll
            for (int m = 0; m < MF; ++m) {
                int row = wr + m * 16 + fr;
                af[m] = *(const short8*)(L + row * 64 + ((kk * 4 + fq) ^ (row & 7)) * 8);
            }
#pragma unroll
            for (int n = 0; n < NF; ++n) {
                int row = BM + wc + n * 16 + fr;
                bf[n] = *(const short8*)(L + row * 64 + ((kk * 4 + fq) ^ (row & 7)) * 8);
            }
#pragma unroll
            for (int m = 0; m < MF; ++m)
#pragma unroll
                for (int n = 0; n < NF; ++n)
                    acc[m][n] = __builtin_amdgcn_mfma_f32_16x16x32_bf16(af[m], bf[n], acc[m][n], 0, 0, 0);
        }
        __builtin_amdgcn_sched_barrier(0);
        __builtin_amdgcn_s_barrier();
        __builtin_amdgcn_sched_barrier(0);
    }

    float* Cf = (float*)Cv;
    unsigned short* Cb = (unsigned short*)Cv;
#pragma unroll
    for (int n = 0; n < NF; ++n) {
        int col = n0 + wc + n * 16 + fr;
        if (col >= N) continue;
        float bv = bias ? bias[col] : 0.f;
#pragma unroll
        for (int m = 0; m < MF; ++m) {
#pragma unroll
            for (int r = 0; r < 4; ++r) {
                int row = m0 + wr + m * 16 + fq * 4 + r;
                if (row >= M) continue;
                float v = acc[m][n][r] + bv;
                if (EPI == 2) v = gelu_tanh(v);
                size_t o = (size_t)row * ldc + col;
                if (EPI == 3) v += Cf[o];
                if (BOUT)      Cb[o] = f2bf(v);
                else if (NTS)  __builtin_nontemporal_store(v, &Cf[o]);
                else           Cf[o] = v;
            }
        }
    }
}

// ---------------- 256x256 8-wave gene GEMM (m201-style fine interleave) --------
// (R12 version — unchanged)
__global__ __launch_bounds__(512, 2) void gemm_gene(const unsigned short* __restrict__ A, int lda,
                                                    const unsigned short* __restrict__ BT, int ldb,
                                                    float* __restrict__ C, int ldc,
                                                    int M, int N, int K) {
    __shared__ __align__(16) short lds[2 * 512 * 64];   // [buf][A 256 rows | B 256 rows][64]

    int bx, by;
    remap_block(bx, by);

    const int tid  = threadIdx.x;
    const int lane = tid & 63;
    const int wid  = tid >> 6;          // 0..7
    const int wm   = wid >> 2;          // 0..1 -> row offset wm*128
    const int wn   = wid & 3;           // 0..3 -> col offset wn*64
    const int fq   = lane >> 4;
    const int fr   = lane & 15;
    const int m0 = by * 256, n0 = bx * 256;

    const int tslot = ((tid & 7) ^ ((tid >> 3) & 7)) * 8;   // pre-swizzled global slot

    f32x4 acc[8][4] = {};

    auto stage = [&](int k0, int buf) {
        short* dst = lds + buf * (512 * 64);
#pragma unroll
        for (int u = 0; u < 8; ++u) {
            int rw = u * 64 + wid * 8;              // wave-uniform base row
            int r  = rw + (lane >> 3);              // this lane's concat row
            const unsigned short* src =
                (r < 256) ? (A  + (size_t)(m0 + r) * lda       + k0 + tslot)
                          : (BT + (size_t)(n0 + r - 256) * ldb + k0 + tslot);
            gload16(src, dst + rw * 64);
        }
    };

    const int nsteps = K >> 6;
    stage(0, 0);
    for (int t = 0; t < nsteps; ++t) {
        const int buf = t & 1;
        if (t + 1 < nsteps) {
            stage((t + 1) << 6, buf ^ 1);
            waitvm<8>();                            // tile t done; t+1's 8 in flight
        } else {
            waitvm<0>();
        }
        __builtin_amdgcn_sched_barrier(0);
        __builtin_amdgcn_s_barrier();
        __builtin_amdgcn_sched_barrier(0);

        const short* L = lds + buf * (512 * 64);
#pragma unroll
        for (int q = 0; q < 4; ++q) {               // quadrant phases, barrier-fenced
            const int mb = (q >> 1) * 4, nb = (q & 1) * 2;
            short8 af[4][2], bf[2][2];
#pragma unroll
            for (int m = 0; m < 4; ++m) {
                int row = wm * 128 + (mb + m) * 16 + fr;
#pragma unroll
                for (int kk = 0; kk < 2; ++kk)
                    af[m][kk] = *(const short8*)(L + row * 64 + ((kk * 4 + fq) ^ (row & 7)) * 8);
            }
#pragma unroll
            for (int n = 0; n < 2; ++n) {
                int row = 256 + wn * 64 + (nb + n) * 16 + fr;
#pragma unroll
                for (int kk = 0; kk < 2; ++kk)
                    bf[n][kk] = *(const short8*)(L + row * 64 + ((kk * 4 + fq) ^ (row & 7)) * 8);
            }
            __builtin_amdgcn_sched_barrier(0);
            __builtin_amdgcn_s_barrier();           // cluster issue phase
            asm volatile("s_waitcnt lgkmcnt(0)" ::: "memory");
            __builtin_amdgcn_sched_barrier(0);      // rule #18: pin MFMA below the wait
            __builtin_amdgcn_s_setprio(1);
#pragma unroll
            for (int kk = 0; kk < 2; ++kk)
#pragma unroll
                for (int m = 0; m < 4; ++m)
#pragma unroll
                    for (int n = 0; n < 2; ++n)
                        acc[mb + m][nb + n] = __builtin_amdgcn_mfma_f32_16x16x32_bf16(
                            af[m][kk], bf[n][kk], acc[mb + m][nb + n], 0, 0, 0);
            __builtin_amdgcn_s_setprio(0);
            __builtin_amdgcn_sched_barrier(0);
            __builtin_amdgcn_s_barrier();           // end of MFMA phase
            __builtin_amdgcn_sched_barrier(0);
        }
    }

#pragma unroll
    for (int n = 0; n < 4; ++n) {
        int col = n0 + wn * 64 + n * 16 + fr;
        if (col >= N) continue;
#pragma unroll
        for (int m = 0; m < 8; ++m) {
#pragma unroll
            for (int r = 0; r < 4; ++r) {
                int row = m0 + wm * 128 + m * 16 + fq * 4 + r;
                if (row >= M) continue;
                __builtin_nontemporal_store(acc[m][n][r], &C[(size_t)row * ldc + col]);
            }
        }
    }
}

// ---------------- launcher ----------------
static inline char* align256(char* p) {
    return (char*)(((uintptr_t)p + 255) & ~(uintptr_t)255);
}

extern "C" void kernel_launch(void* const* d_in, const int* in_sizes, int n_in,
                              void* d_out, int out_size, void* d_ws, size_t ws_size,
                              hipStream_t stream) {
    const int*   idxs = (const int*)d_in[0];
    const float* fro  = (const float*)d_in[1];
    const int*   eidx = (const int*)d_in[2];
    const float* ew   = (const float*)d_in[3];
    const float* W6   = (const float*)d_in[4];
    const float* b6   = (const float*)d_in[5];
    const float* W7   = (const float*)d_in[6];
    const float* b7   = (const float*)d_in[7];
    const float* Wp   = (const float*)d_in[8];
    const float* bp   = (const float*)d_in[9];
    const float* oov  = (const float*)d_in[10];
    const float* in_g = (const float*)d_in[11];
    const float* in_b = (const float*)d_in[12];
    const float* inW  = (const float*)d_in[13];
    const float* inb  = (const float*)d_in[14];
    const float* bg   = (const float*)d_in[15];
    const float* bb   = (const float*)d_in[16];
    const float* f1W  = (const float*)d_in[17];
    const float* f1b  = (const float*)d_in[18];
    const float* f2W  = (const float*)d_in[19];
    const float* f2b  = (const float*)d_in[20];
    const float* og   = (const float*)d_in[21];
    const float* ob   = (const float*)d_in[22];
    const float* oW   = (const float*)d_in[23];
    const float* obia = (const float*)d_in[24];
    const float* gene = (const float*)d_in[25];
    float* out = (float*)d_out;

    // ---- workspace carve-up ----
    char* p = (char*)d_ws;
    auto alloc_f = [&](size_t n) { float* r = (float*)p; p = align256(p + n * 4); return r; };
    auto alloc_i = [&](size_t n) { int*   r = (int*)p;   p = align256(p + n * 4); return r; };
    auto alloc_h = [&](size_t n) { unsigned short* r = (unsigned short*)p; p = align256(p + n * 2); return r; };

    float* X    = alloc_f((size_t)N_NODES * DDIM);
    unsigned short* Yb = alloc_h((size_t)N_NODES * DDIM);
    int*   cnt  = alloc_i(N_NODES);
    int*   mark = alloc_i(N_NODES);
    int*   off  = alloc_i(N_NODES + 1);
    int*   cur  = alloc_i(N_NODES);
    int*   ssrc = alloc_i(N_EDGES);
    float* sw   = alloc_f(N_EDGES);
    unsigned short* Xb  = alloc_h((size_t)N_PAD * DDIM);      // padded rows for gload_lds
    unsigned short* Ag  = alloc_h((size_t)NBATCH * DDIM);
    float* Zp   = alloc_f((size_t)NBATCH * DDIM);
    unsigned short* HN256 = alloc_h((size_t)NBATCH * DDIM);
    float* H    = alloc_f((size_t)NBATCH * HIDD);
    unsigned short* HN512 = alloc_h((size_t)NBATCH * HIDD);
    unsigned short* Tb  = alloc_h((size_t)NBATCH * HEXP);
    unsigned short* PPb = alloc_h((size_t)NBATCH * NCLS * RNK);
    unsigned short* W6T  = alloc_h((size_t)DDIM * DDIM);
    unsigned short* W7T  = alloc_h((size_t)DDIM * DDIM);
    unsigned short* WpT  = alloc_h((size_t)DDIM * DDIM);
    unsigned short* inWT = alloc_h((size_t)HIDD * DDIM);
    unsigned short* f1WT = alloc_h((size_t)NBLK * HIDD * HEXP);
    unsigned short* f2WT = alloc_h((size_t)NBLK * HIDD * HEXP);
    unsigned short* oWT  = alloc_h((size_t)NCLS * RNK * HIDD);
    unsigned short* geneB= alloc_h((size_t)NGPAD * RNK);       // padded rows

    const int* esrc = eidx;
    const int* edst = eidx + N_EDGES;
    dim3 blk(256);

    // ---- weight prep (+cnt/mark zero tail) and init/gene/mark ----
    prep_all_kernel<<<dim3(PREP_TILES + 2 * ZERO_BLKS), blk, 0, stream>>>(
        W6, W7, Wp, inW, f1W, f2W, oW, W6T, W7T, WpT, inWT, f1WT, f2WT, oWT, cnt, mark);
    const int node4 = N_NODES * DDIM / 4;
    const int gene4 = NGENE * RNK / 4;
    init_and_gene_kernel<<<dim3((node4 + gene4 + NBATCH + 255) / 256), blk, 0, stream>>>(
        (const float4*)fro, (float4*)X, (ushort4*)Xb, node4, gene, geneB, gene4, idxs, mark);

    // ---- CSR build (by dst) ----
    hist_kernel<<<dim3(N_EDGES / 256), blk, 0, stream>>>(edst, cnt);
    scan_kernel<<<dim3(1), blk, 0, stream>>>(cnt, off, cur);
    fill_kernel<<<dim3(N_EDGES / 256), blk, 0, stream>>>(esrc, edst, ew, cur, ssrc, sw);

    // ---- GNN tail ----
    dim3 gnn_grid(DDIM / 128, N_PAD / 128);
    gemm_mfma<128, 128, 0, true><<<gnn_grid, blk, 0, stream>>>(
        Xb, DDIM, W6T, DDIM, Yb, DDIM, nullptr, N_NODES, DDIM, DDIM);
    agg_update_kernel<true><<<dim3(N_NODES / 4), blk, 0, stream>>>(
        Yb, off, ssrc, sw, b6, X, Xb, nullptr);
    gemm_mfma<128, 128, 0, true><<<gnn_grid, blk, 0, stream>>>(
        Xb, DDIM, W7T, DDIM, Yb, DDIM, nullptr, N_NODES, DDIM, DDIM);
    // layer 2: X is only read via gather -> update only gathered (marked) nodes
    agg_update_kernel<false><<<dim3(N_NODES / 4), blk, 0, stream>>>(
        Yb, off, ssrc, sw, b7, X, nullptr, mark);

    // project only gathered rows: Ag = bf16(X[clip(idx)]), Zp = Ag @ Wp + bp
    gather_cvt_kernel<<<dim3(NBATCH), blk, 0, stream>>>(X, idxs, Ag);
    gemm_mfma<64, 128, 0, false><<<dim3(DDIM / 128, NBATCH / 64), blk, 0, stream>>>(
        Ag, DDIM, WpT, DDIM, Zp, DDIM, bp, NBATCH, DDIM, DDIM);
    // oov-select + input LN fused
    ln_oov_kernel<<<dim3(NBATCH), blk, 0, stream>>>(Zp, idxs, oov, in_g, in_b, HN256);

    // ---- head ----
    // inW: BM=32 -> 512 blocks (2/CU occupancy fix)
    gemm_mfma<32, 128, 0, false><<<dim3(HIDD / 128, NBATCH / 32), blk, 0, stream>>>(
        HN256, DDIM, inWT, DDIM, H, HIDD, inb, NBATCH, HIDD, DDIM);
    for (int i = 0; i < NBLK; ++i) {
        ln_kernel<<<dim3(NBATCH), blk, 0, stream>>>(H, bg + (size_t)i * HIDD,
                                                    bb + (size_t)i * HIDD, HN512, HIDD);
        gemm_mfma<128, 128, 2, true><<<dim3(HEXP / 128, NBATCH / 128), blk, 0, stream>>>(
            HN512, HIDD, f1WT + (size_t)i * HEXP * HIDD, HIDD, Tb, HEXP,
            f1b + (size_t)i * HEXP, NBATCH, HEXP, HIDD);
        // fc2: BM=32 -> 512 blocks (2/CU occupancy fix)
        gemm_mfma<32, 128, 3, false><<<dim3(HIDD / 128, NBATCH / 32), blk, 0, stream>>>(
            Tb, HEXP, f2WT + (size_t)i * HIDD * HEXP, HEXP, H, HIDD,
            f2b + (size_t)i * HIDD, NBATCH, HIDD, HEXP);
    }
    ln_kernel<<<dim3(NBATCH), blk, 0, stream>>>(H, og, ob, HN512, HIDD);
    gemm_mfma<128, 128, 0, true><<<dim3(NCLS * RNK / 128, NBATCH / 128), blk, 0, stream>>>(
        HN512, HIDD, oWT, HIDD, PPb, NCLS * RNK, obia, NBATCH, NCLS * RNK, HIDD);

    // ---- bilinear gene head: 256x256 8-wave fine-interleaved kernel ----
    gemm_gene<<<dim3(NGPAD / 256, NBATCH * NCLS / 256), dim3(512), 0, stream>>>(
        PPb, RNK, geneB, RNK, out, NGENE, NBATCH * NCLS, NGENE, RNK);
}

// Round 15
// 787.239 us; speedup vs baseline: 1.0497x; 1.0310x over previous
//
#include <hip/hip_runtime.h>
#include <cstdint>
#include <cstddef>

#define N_NODES 20000
#define N_PAD   20096   // 157*128
#define N_EDGES 640000
#define DDIM    256
#define HIDD    512
#define NBLK    6
#define HEXP    2048    // HID*EXP
#define NCLS    3
#define RNK     512
#define NGENE   6640
#define NGPAD   6656    // 26*256
#define NBATCH  4096

typedef __attribute__((ext_vector_type(8))) short short8;
typedef __attribute__((ext_vector_type(4))) float f32x4;

__device__ __forceinline__ float gelu_tanh(float x) {
    float x3 = x * x * x;
    return 0.5f * x * (1.f + tanhf(0.7978845608028654f * (x + 0.044715f * x3)));
}

// f32 -> bf16 RNE bit pattern
__device__ __forceinline__ unsigned short f2bf(float f) {
    unsigned u = __float_as_uint(f);
    unsigned r = (u + 0x7FFFu + ((u >> 16) & 1u)) >> 16;
    return (unsigned short)r;
}

__device__ __forceinline__ float bf2f(unsigned short h) {
    return __uint_as_float((unsigned)h << 16);
}

// async global->LDS, 16B per lane. LDS dest is wave-uniform base + lane*16.
__device__ __forceinline__ void gload16(const unsigned short* g, short* l) {
    __builtin_amdgcn_global_load_lds(
        (const __attribute__((address_space(1))) void*)g,
        (__attribute__((address_space(3))) void*)l, 16, 0, 0);
}

// counted vmcnt wait (immediate must be literal)
template <int N>
__device__ __forceinline__ void waitvm() {
    if constexpr (N == 0)      asm volatile("s_waitcnt vmcnt(0)" ::: "memory");
    else if constexpr (N == 5) asm volatile("s_waitcnt vmcnt(5)" ::: "memory");
    else if constexpr (N == 6) asm volatile("s_waitcnt vmcnt(6)" ::: "memory");
    else if constexpr (N == 8) asm volatile("s_waitcnt vmcnt(8)" ::: "memory");
    else if constexpr (N == 12) asm volatile("s_waitcnt vmcnt(12)" ::: "memory");
    else static_assert(N == 0, "unsupported vmcnt");
}

// block remap: XCD-bijective chunking (m204) + 16-row supertiles for L2 reuse.
__device__ __forceinline__ void remap_block(int& bx, int& by) {
    const int NBX = gridDim.x, NBY = gridDim.y;
    const int nwg = NBX * NBY;
    int orig = blockIdx.y * NBX + blockIdx.x;
    int q = nwg >> 3, r = nwg & 7;
    int xcd = orig & 7, lid = orig >> 3;
    int w = (xcd < r ? xcd * (q + 1) : r * (q + 1) + (xcd - r) * q) + lid;
    int G = NBY < 16 ? NBY : 16;
    int per = G * NBX;
    int full = NBY / G;
    if (w < full * per) {
        int g = w / per, rem = w % per;
        bx = rem / G;
        by = g * G + (rem % G);
    } else {
        int w2 = w - full * per;
        int tG = NBY - full * G;
        bx = w2 / tG;
        by = full * G + w2 % tG;
    }
}

// ---------------- utility kernels ----------------
// merged: initX + gene f32->bf16 convert + gathered-node marking
__global__ __launch_bounds__(256) void init_and_gene_kernel(const float4* __restrict__ fro,
                                                            float4* __restrict__ X,
                                                            ushort4* __restrict__ Xb, int n4x,
                                                            const float* __restrict__ gene,
                                                            unsigned short* __restrict__ geneB,
                                                            int n4g,
                                                            const int* __restrict__ idxs,
                                                            int* __restrict__ mark) {
    int i = blockIdx.x * 256 + threadIdx.x;
    if (i < n4x) {
        float4 v = fro[i];
        X[i] = v;
        ushort4 h;
        h.x = f2bf(v.x); h.y = f2bf(v.y); h.z = f2bf(v.z); h.w = f2bf(v.w);
        Xb[i] = h;
    } else if (i < n4x + n4g) {
        int j = i - n4x;
        float4 v = ((const float4*)gene)[j];
        ushort4 o;
        o.x = f2bf(v.x); o.y = f2bf(v.y); o.z = f2bf(v.z); o.w = f2bf(v.w);
        ((ushort4*)geneB)[j] = o;
    } else {
        int b = i - n4x - n4g;
        if (b < NBATCH) {
            int id = idxs[b];
            mark[id < 0 ? 0 : id] = 1;   // benign race: all write 1
        }
    }
}

// ---------------- fused weight prep (+ cnt/mark zeroing tail blocks) ----------------
#define PREP_TILES 13376
#define ZERO_BLKS  ((N_NODES + 255) / 256)   // 79
__global__ __launch_bounds__(256) void prep_all_kernel(
        const float* W6, const float* W7, const float* Wp, const float* inW,
        const float* f1W, const float* f2W, const float* oW,
        unsigned short* W6T, unsigned short* W7T, unsigned short* WpT, unsigned short* inWT,
        unsigned short* f1WT, unsigned short* f2WT, unsigned short* oWT,
        int* cnt, int* mark) {
    int id = blockIdx.x;
    if (id >= PREP_TILES) {           // tail blocks: zero CSR histogram + mark flags
        int z = id - PREP_TILES;
        if (z < ZERO_BLKS) {
            int i = z * 256 + threadIdx.x;
            if (i < N_NODES) cnt[i] = 0;
        } else {
            int i = (z - ZERO_BLKS) * 256 + threadIdx.x;
            if (i < N_NODES) mark[i] = 0;
        }
        return;
    }
    const float* in; unsigned short* out; int R, C, nx, local;
    if (id < 192) {            // W6/W7/Wp
        int m = id / 64; local = id % 64;
        in = m == 0 ? W6 : (m == 1 ? W7 : Wp);
        out = m == 0 ? W6T : (m == 1 ? W7T : WpT);
        R = DDIM; C = DDIM; nx = 8;
    } else if (id < 320) {     // inW 256x512
        local = id - 192; in = inW; out = inWT; R = DDIM; C = HIDD; nx = 16;
    } else if (id < 6464) {    // f1W 6 x 512x2048
        local = id - 320; int layer = local / 1024; local %= 1024;
        in = f1W + (size_t)layer * HIDD * HEXP; out = f1WT + (size_t)layer * HEXP * HIDD;
        R = HIDD; C = HEXP; nx = 64;
    } else if (id < 12608) {   // f2W 6 x 2048x512
        local = id - 6464; int layer = local / 1024; local %= 1024;
        in = f2W + (size_t)layer * HEXP * HIDD; out = f2WT + (size_t)layer * HIDD * HEXP;
        R = HEXP; C = HIDD; nx = 16;
    } else {                   // oW 512x1536
        local = id - 12608; in = oW; out = oWT; R = HIDD; C = NCLS * RNK; nx = 48;
    }
    int bx = local % nx, by = local / nx;
    __shared__ float tile[32][33];
    int c0 = bx * 32, r0 = by * 32;
    int tx = threadIdx.x & 31, ty = threadIdx.x >> 5;
#pragma unroll
    for (int i = 0; i < 4; ++i) {
        int r = r0 + ty + i * 8, c = c0 + tx;
        tile[ty + i * 8][tx] = (r < R && c < C) ? in[(size_t)r * C + c] : 0.f;
    }
    __syncthreads();
#pragma unroll
    for (int i = 0; i < 4; ++i) {
        int c = c0 + ty + i * 8, r = r0 + tx;
        if (c < C && r < R) out[(size_t)c * R + r] = f2bf(tile[tx][ty + i * 8]);
    }
}

// ---------------- CSR build ----------------
__global__ __launch_bounds__(256) void hist_kernel(const int* __restrict__ dst,
                                                   int* __restrict__ cnt) {
    int e = blockIdx.x * 256 + threadIdx.x;
    if (e < N_EDGES) atomicAdd(&cnt[dst[e]], 1);
}

__global__ __launch_bounds__(256) void scan_kernel(const int* __restrict__ cnt,
                                                   int* __restrict__ off,
                                                   int* __restrict__ cur) {
    __shared__ int part[256];
    const int CH = (N_NODES + 255) / 256;
    int t = threadIdx.x;
    int base = t * CH;
    int s = 0;
    for (int j = 0; j < CH; ++j) {
        int i = base + j;
        if (i < N_NODES) s += cnt[i];
    }
    part[t] = s;
    __syncthreads();
    for (int d = 1; d < 256; d <<= 1) {
        int v = (t >= d) ? part[t - d] : 0;
        __syncthreads();
        part[t] += v;
        __syncthreads();
    }
    int run = part[t] - s;
    for (int j = 0; j < CH; ++j) {
        int i = base + j;
        if (i < N_NODES) {
            off[i] = run; cur[i] = run;
            run += cnt[i];
        }
    }
    if (t == 255) off[N_NODES] = run;
}

__global__ __launch_bounds__(256) void fill_kernel(const int* __restrict__ src,
                                                   const int* __restrict__ dst,
                                                   const float* __restrict__ ew,
                                                   int* __restrict__ cur,
                                                   int* __restrict__ ssrc,
                                                   float* __restrict__ sw) {
    int e = blockIdx.x * 256 + threadIdx.x;
    if (e >= N_EDGES) return;
    int slot = atomicAdd(&cur[dst[e]], 1);
    ssrc[slot] = src[e];
    sw[slot]   = ew[e];
}

// fused aggregation + update, one wave per node, bf16 Y rows, 4-deep unrolled.
// mark != nullptr: only process marked nodes (layer-2: only gathered nodes are read)
template <bool WB>
__global__ __launch_bounds__(256) void agg_update_kernel(const unsigned short* __restrict__ Y,
                                                         const int* __restrict__ off,
                                                         const int* __restrict__ ssrc,
                                                         const float* __restrict__ sw,
                                                         const float* __restrict__ bias,
                                                         float* __restrict__ X,
                                                         unsigned short* __restrict__ Xb,
                                                         const int* __restrict__ mark) {
    int node = blockIdx.x * 4 + (threadIdx.x >> 6);
    int lane = threadIdx.x & 63;
    if (mark != nullptr && mark[node] == 0) return;   // wave-uniform
    int b = off[node], e = off[node + 1];
    const ushort4* Yv = (const ushort4*)Y;
    float4 acc = make_float4(0.f, 0.f, 0.f, 0.f);
    int j = b;
    for (; j + 3 < e; j += 4) {
        int s0 = ssrc[j], s1 = ssrc[j + 1], s2 = ssrc[j + 2], s3 = ssrc[j + 3];
        float w0 = sw[j], w1 = sw[j + 1], w2 = sw[j + 2], w3 = sw[j + 3];
        ushort4 v0 = Yv[(size_t)s0 * 64 + lane];
        ushort4 v1 = Yv[(size_t)s1 * 64 + lane];
        ushort4 v2 = Yv[(size_t)s2 * 64 + lane];
        ushort4 v3 = Yv[(size_t)s3 * 64 + lane];
        acc.x += bf2f(v0.x) * w0 + bf2f(v1.x) * w1 + bf2f(v2.x) * w2 + bf2f(v3.x) * w3;
        acc.y += bf2f(v0.y) * w0 + bf2f(v1.y) * w1 + bf2f(v2.y) * w2 + bf2f(v3.y) * w3;
        acc.z += bf2f(v0.z) * w0 + bf2f(v1.z) * w1 + bf2f(v2.z) * w2 + bf2f(v3.z) * w3;
        acc.w += bf2f(v0.w) * w0 + bf2f(v1.w) * w1 + bf2f(v2.w) * w2 + bf2f(v3.w) * w3;
    }
    for (; j < e; ++j) {
        int s = ssrc[j];
        float w = sw[j];
        ushort4 v = Yv[(size_t)s * 64 + lane];
        acc.x += bf2f(v.x) * w; acc.y += bf2f(v.y) * w;
        acc.z += bf2f(v.z) * w; acc.w += bf2f(v.w) * w;
    }
    float4 bv = ((const float4*)bias)[lane];
    size_t o = (size_t)node * 64 + lane;
    float4 x = ((float4*)X)[o];
    x.x += fmaxf(acc.x + bv.x, 0.f);
    x.y += fmaxf(acc.y + bv.y, 0.f);
    x.z += fmaxf(acc.z + bv.z, 0.f);
    x.w += fmaxf(acc.w + bv.w, 0.f);
    ((float4*)X)[o] = x;
    if (WB) {
        ushort4 h;
        h.x = f2bf(x.x); h.y = f2bf(x.y); h.z = f2bf(x.z); h.w = f2bf(x.w);
        ((ushort4*)Xb)[o] = h;
    }
}

// gather rows of X (f32) at clip(idx,0) -> bf16 [NBATCH][DDIM]; one wave per row
__global__ __launch_bounds__(256) void gather_cvt_kernel(const float* __restrict__ X,
                                                         const int* __restrict__ idxs,
                                                         unsigned short* __restrict__ Ag) {
    int b = blockIdx.x * 4 + (threadIdx.x >> 6);
    int lane = threadIdx.x & 63;
    int id = idxs[b];
    if (id < 0) id = 0;
    float4 v = *(const float4*)(X + (size_t)id * DDIM + lane * 4);
    ushort4 o;
    o.x = f2bf(v.x); o.y = f2bf(v.y); o.z = f2bf(v.z); o.w = f2bf(v.w);
    *(ushort4*)(Ag + (size_t)b * DDIM + lane * 4) = o;
}

// LN over 256 cols with OOV substitution, one WAVE per row (4 cols/lane), bf16 out
__global__ __launch_bounds__(256) void ln_oov_kernel(const float* __restrict__ Z,
                                                     const int* __restrict__ idxs,
                                                     const float* __restrict__ oov,
                                                     const float* __restrict__ g,
                                                     const float* __restrict__ bb,
                                                     unsigned short* __restrict__ Y) {
    int row = blockIdx.x * 4 + (threadIdx.x >> 6);
    int lane = threadIdx.x & 63;
    int id = idxs[row];
    float4 v = (id >= 0) ? *(const float4*)(Z + (size_t)row * DDIM + lane * 4)
                         : *(const float4*)(oov + lane * 4);
    float sum = v.x + v.y + v.z + v.w;
    float sq  = v.x * v.x + v.y * v.y + v.z * v.z + v.w * v.w;
#pragma unroll
    for (int m = 1; m < 64; m <<= 1) {
        sum += __shfl_xor(sum, m);
        sq  += __shfl_xor(sq, m);
    }
    float mu  = sum * (1.f / DDIM);
    float var = sq * (1.f / DDIM) - mu * mu;
    float r   = rsqrtf(var + 1e-5f);
    float4 gv = *(const float4*)(g + lane * 4);
    float4 bv = *(const float4*)(bb + lane * 4);
    ushort4 o;
    o.x = f2bf((v.x - mu) * r * gv.x + bv.x);
    o.y = f2bf((v.y - mu) * r * gv.y + bv.y);
    o.z = f2bf((v.z - mu) * r * gv.z + bv.z);
    o.w = f2bf((v.w - mu) * r * gv.w + bv.w);
    *(ushort4*)(Y + (size_t)row * DDIM + lane * 4) = o;
}

// LN over 512 cols, one WAVE per row (8 cols/lane), f32 in -> bf16 out
__global__ __launch_bounds__(256) void ln512_kernel(const float* __restrict__ X,
                                                    const float* __restrict__ g,
                                                    const float* __restrict__ bb,
                                                    unsigned short* __restrict__ Y) {
    int row = blockIdx.x * 4 + (threadIdx.x >> 6);
    int lane = threadIdx.x & 63;
    const float* x = X + (size_t)row * HIDD + lane * 8;
    float4 a = *(const float4*)x;
    float4 b = *(const float4*)(x + 4);
    float sum = a.x + a.y + a.z + a.w + b.x + b.y + b.z + b.w;
    float sq  = a.x * a.x + a.y * a.y + a.z * a.z + a.w * a.w
              + b.x * b.x + b.y * b.y + b.z * b.z + b.w * b.w;
#pragma unroll
    for (int m = 1; m < 64; m <<= 1) {
        sum += __shfl_xor(sum, m);
        sq  += __shfl_xor(sq, m);
    }
    float mu  = sum * (1.f / HIDD);
    float var = sq * (1.f / HIDD) - mu * mu;
    float r   = rsqrtf(var + 1e-5f);
    const float* gp = g + lane * 8;
    const float* bp = bb + lane * 8;
    float4 g0 = *(const float4*)gp, g1 = *(const float4*)(gp + 4);
    float4 b0 = *(const float4*)bp, b1 = *(const float4*)(bp + 4);
    ushort4 o0, o1;
    o0.x = f2bf((a.x - mu) * r * g0.x + b0.x);
    o0.y = f2bf((a.y - mu) * r * g0.y + b0.y);
    o0.z = f2bf((a.z - mu) * r * g0.z + b0.z);
    o0.w = f2bf((a.w - mu) * r * g0.w + b0.w);
    o1.x = f2bf((b.x - mu) * r * g1.x + b1.x);
    o1.y = f2bf((b.y - mu) * r * g1.y + b1.y);
    o1.z = f2bf((b.z - mu) * r * g1.z + b1.z);
    o1.w = f2bf((b.w - mu) * r * g1.w + b1.w);
    unsigned short* y = Y + (size_t)row * HIDD + lane * 8;
    *(ushort4*)y       = o0;
    *(ushort4*)(y + 4) = o1;
}

// ---------------- bf16 MFMA GEMM (dbuf + counted vmcnt pipeline) ----------------
// R6/R12-proven form: 256 threads = 4 waves (2x2), wave tile (BM/2)x(BN/2),
// BK=64, double-buffered LDS, counted vmcnt (never 0 mid-loop) + raw s_barrier.
// BM=32 variant (MF=1) doubles blocks/CU for N<=512 shapes (occupancy fix).
// EPI: 0 = +bias ; 2 = gelu(+bias) ; 3 = C(f32) += (+bias).  BOUT: bf16 store.
// NTS: non-temporal C store.
template <int BM, int BN, int EPI, bool BOUT, bool NTS = false>
__global__ __launch_bounds__(256) void gemm_mfma(const unsigned short* __restrict__ A, int lda,
                                                 const unsigned short* __restrict__ BT, int ldb,
                                                 void* __restrict__ Cv, int ldc,
                                                 const float* __restrict__ bias,
                                                 int M, int N, int K) {
    constexpr int WM = BM / 2, WN = BN / 2;
    constexpr int MF = WM / 16, NF = WN / 16;
    constexpr int ROWS  = BM + BN;
    constexpr int NCALL = ROWS / 32;       // gload16 per wave per k-tile
    __shared__ __align__(16) short lds[2 * ROWS * 64];

    int bx, by;
    remap_block(bx, by);

    const int tid  = threadIdx.x;
    const int lane = tid & 63;
    const int wid  = tid >> 6;
    const int wr   = (wid >> 1) * WM;
    const int wc   = (wid & 1) * WN;
    const int fq   = lane >> 4;
    const int fr   = lane & 15;
    const int m0 = by * BM, n0 = bx * BN;

    const int srow  = lane >> 3;                   // row within 8-row chunk
    const int tslot = ((lane & 7) ^ srow) * 8;     // pre-swizzled global slot (elems)

    f32x4 acc[MF][NF] = {};

    auto stage = [&](int k0, int buf) {
        short* dst = lds + buf * (ROWS * 64);
#pragma unroll
        for (int c = 0; c < NCALL; ++c) {
            int r = c * 32 + wid * 8 + srow;       // concatenated row (A then B)
            const unsigned short* src =
                (r < BM) ? (A  + (size_t)(m0 + r) * lda      + k0 + tslot)
                         : (BT + (size_t)(n0 + r - BM) * ldb + k0 + tslot);
            gload16(src, dst + (c * 32 + wid * 8) * 64);
        }
    };

    const int nsteps = K >> 6;
    stage(0, 0);
    for (int t = 0; t < nsteps; ++t) {
        const int buf = t & 1;
        if (t + 1 < nsteps) {
            stage((t + 1) << 6, buf ^ 1);
            waitvm<NCALL>();                       // tile t done; t+1 stays in flight
        } else {
            waitvm<0>();
        }
        __builtin_amdgcn_sched_barrier(0);
        __builtin_amdgcn_s_barrier();
        __builtin_amdgcn_sched_barrier(0);

        const short* L = lds + buf * (ROWS * 64);
#pragma unroll
        for (int kk = 0; kk < 2; ++kk) {
            short8 af[MF], bf[NF];
#pragma unroll
            for (int m = 0; m < MF; ++m) {
                int row = wr + m * 16 + fr;
                af[m] = *(const short8*)(L + row * 64 + ((kk * 4 + fq) ^ (row & 7)) * 8);
            }
#pragma unroll
            for (int n = 0; n < NF; ++n) {
                int row = BM + wc + n * 16 + fr;
                bf[n] = *(const short8*)(L + row * 64 + ((kk * 4 + fq) ^ (row & 7)) * 8);
            }
#pragma unroll
            for (int m = 0; m < MF; ++m)
#pragma unroll
                for (int n = 0; n < NF; ++n)
                    acc[m][n] = __builtin_amdgcn_mfma_f32_16x16x32_bf16(af[m], bf[n], acc[m][n], 0, 0, 0);
        }
        __builtin_amdgcn_sched_barrier(0);
        __builtin_amdgcn_s_barrier();
        __builtin_amdgcn_sched_barrier(0);
    }

    float* Cf = (float*)Cv;
    unsigned short* Cb = (unsigned short*)Cv;
#pragma unroll
    for (int n = 0; n < NF; ++n) {
        int col = n0 + wc + n * 16 + fr;
        if (col >= N) continue;
        float bv = bias ? bias[col] : 0.f;
#pragma unroll
        for (int m = 0; m < MF; ++m) {
#pragma unroll
            for (int r = 0; r < 4; ++r) {
                int row = m0 + wr + m * 16 + fq * 4 + r;
                if (row >= M) continue;
                float v = acc[m][n][r] + bv;
                if (EPI == 2) v = gelu_tanh(v);
                size_t o = (size_t)row * ldc + col;
                if (EPI == 3) v += Cf[o];
                if (BOUT)      Cb[o] = f2bf(v);
                else if (NTS)  __builtin_nontemporal_store(v, &Cf[o]);
                else           Cf[o] = v;
            }
        }
    }
}

// ---------------- 256x256 8-wave gene GEMM (m201-style fine interleave) --------
// (R12 version — unchanged)
__global__ __launch_bounds__(512, 2) void gemm_gene(const unsigned short* __restrict__ A, int lda,
                                                    const unsigned short* __restrict__ BT, int ldb,
                                                    float* __restrict__ C, int ldc,
                                                    int M, int N, int K) {
    __shared__ __align__(16) short lds[2 * 512 * 64];   // [buf][A 256 rows | B 256 rows][64]

    int bx, by;
    remap_block(bx, by);

    const int tid  = threadIdx.x;
    const int lane = tid & 63;
    const int wid  = tid >> 6;          // 0..7
    const int wm   = wid >> 2;          // 0..1 -> row offset wm*128
    const int wn   = wid & 3;           // 0..3 -> col offset wn*64
    const int fq   = lane >> 4;
    const int fr   = lane & 15;
    const int m0 = by * 256, n0 = bx * 256;

    const int tslot = ((tid & 7) ^ ((tid >> 3) & 7)) * 8;   // pre-swizzled global slot

    f32x4 acc[8][4] = {};

    auto stage = [&](int k0, int buf) {
        short* dst = lds + buf * (512 * 64);
#pragma unroll
        for (int u = 0; u < 8; ++u) {
            int rw = u * 64 + wid * 8;              // wave-uniform base row
            int r  = rw + (lane >> 3);              // this lane's concat row
            const unsigned short* src =
                (r < 256) ? (A  + (size_t)(m0 + r) * lda       + k0 + tslot)
                          : (BT + (size_t)(n0 + r - 256) * ldb + k0 + tslot);
            gload16(src, dst + rw * 64);
        }
    };

    const int nsteps = K >> 6;
    stage(0, 0);
    for (int t = 0; t < nsteps; ++t) {
        const int buf = t & 1;
        if (t + 1 < nsteps) {
            stage((t + 1) << 6, buf ^ 1);
            waitvm<8>();                            // tile t done; t+1's 8 in flight
        } else {
            waitvm<0>();
        }
        __builtin_amdgcn_sched_barrier(0);
        __builtin_amdgcn_s_barrier();
        __builtin_amdgcn_sched_barrier(0);

        const short* L = lds + buf * (512 * 64);
#pragma unroll
        for (int q = 0; q < 4; ++q) {               // quadrant phases, barrier-fenced
            const int mb = (q >> 1) * 4, nb = (q & 1) * 2;
            short8 af[4][2], bf[2][2];
#pragma unroll
            for (int m = 0; m < 4; ++m) {
                int row = wm * 128 + (mb + m) * 16 + fr;
#pragma unroll
                for (int kk = 0; kk < 2; ++kk)
                    af[m][kk] = *(const short8*)(L + row * 64 + ((kk * 4 + fq) ^ (row & 7)) * 8);
            }
#pragma unroll
            for (int n = 0; n < 2; ++n) {
                int row = 256 + wn * 64 + (nb + n) * 16 + fr;
#pragma unroll
                for (int kk = 0; kk < 2; ++kk)
                    bf[n][kk] = *(const short8*)(L + row * 64 + ((kk * 4 + fq) ^ (row & 7)) * 8);
            }
            __builtin_amdgcn_sched_barrier(0);
            __builtin_amdgcn_s_barrier();           // cluster issue phase
            asm volatile("s_waitcnt lgkmcnt(0)" ::: "memory");
            __builtin_amdgcn_sched_barrier(0);      // rule #18: pin MFMA below the wait
            __builtin_amdgcn_s_setprio(1);
#pragma unroll
            for (int kk = 0; kk < 2; ++kk)
#pragma unroll
                for (int m = 0; m < 4; ++m)
#pragma unroll
                    for (int n = 0; n < 2; ++n)
                        acc[mb + m][nb + n] = __builtin_amdgcn_mfma_f32_16x16x32_bf16(
                            af[m][kk], bf[n][kk], acc[mb + m][nb + n], 0, 0, 0);
            __builtin_amdgcn_s_setprio(0);
            __builtin_amdgcn_sched_barrier(0);
            __builtin_amdgcn_s_barrier();           // end of MFMA phase
            __builtin_amdgcn_sched_barrier(0);
        }
    }

#pragma unroll
    for (int n = 0; n < 4; ++n) {
        int col = n0 + wn * 64 + n * 16 + fr;
        if (col >= N) continue;
#pragma unroll
        for (int m = 0; m < 8; ++m) {
#pragma unroll
            for (int r = 0; r < 4; ++r) {
                int row = m0 + wm * 128 + m * 16 + fq * 4 + r;
                if (row >= M) continue;
                __builtin_nontemporal_store(acc[m][n][r], &C[(size_t)row * ldc + col]);
            }
        }
    }
}

// ---------------- launcher ----------------
static inline char* align256(char* p) {
    return (char*)(((uintptr_t)p + 255) & ~(uintptr_t)255);
}

extern "C" void kernel_launch(void* const* d_in, const int* in_sizes, int n_in,
                              void* d_out, int out_size, void* d_ws, size_t ws_size,
                              hipStream_t stream) {
    const int*   idxs = (const int*)d_in[0];
    const float* fro  = (const float*)d_in[1];
    const int*   eidx = (const int*)d_in[2];
    const float* ew   = (const float*)d_in[3];
    const float* W6   = (const float*)d_in[4];
    const float* b6   = (const float*)d_in[5];
    const float* W7   = (const float*)d_in[6];
    const float* b7   = (const float*)d_in[7];
    const float* Wp   = (const float*)d_in[8];
    const float* bp   = (const float*)d_in[9];
    const float* oov  = (const float*)d_in[10];
    const float* in_g = (const float*)d_in[11];
    const float* in_b = (const float*)d_in[12];
    const float* inW  = (const float*)d_in[13];
    const float* inb  = (const float*)d_in[14];
    const float* bg   = (const float*)d_in[15];
    const float* bb   = (const float*)d_in[16];
    const float* f1W  = (const float*)d_in[17];
    const float* f1b  = (const float*)d_in[18];
    const float* f2W  = (const float*)d_in[19];
    const float* f2b  = (const float*)d_in[20];
    const float* og   = (const float*)d_in[21];
    const float* ob   = (const float*)d_in[22];
    const float* oW   = (const float*)d_in[23];
    const float* obia = (const float*)d_in[24];
    const float* gene = (const float*)d_in[25];
    float* out = (float*)d_out;

    // ---- workspace carve-up ----
    char* p = (char*)d_ws;
    auto alloc_f = [&](size_t n) { float* r = (float*)p; p = align256(p + n * 4); return r; };
    auto alloc_i = [&](size_t n) { int*   r = (int*)p;   p = align256(p + n * 4); return r; };
    auto alloc_h = [&](size_t n) { unsigned short* r = (unsigned short*)p; p = align256(p + n * 2); return r; };

    float* X    = alloc_f((size_t)N_NODES * DDIM);
    unsigned short* Yb = alloc_h((size_t)N_NODES * DDIM);
    int*   cnt  = alloc_i(N_NODES);
    int*   mark = alloc_i(N_NODES);
    int*   off  = alloc_i(N_NODES + 1);
    int*   cur  = alloc_i(N_NODES);
    int*   ssrc = alloc_i(N_EDGES);
    float* sw   = alloc_f(N_EDGES);
    unsigned short* Xb  = alloc_h((size_t)N_PAD * DDIM);      // padded rows for gload_lds
    unsigned short* Ag  = alloc_h((size_t)NBATCH * DDIM);
    float* Zp   = alloc_f((size_t)NBATCH * DDIM);
    unsigned short* HN256 = alloc_h((size_t)NBATCH * DDIM);
    float* H    = alloc_f((size_t)NBATCH * HIDD);
    unsigned short* HN512 = alloc_h((size_t)NBATCH * HIDD);
    unsigned short* Tb  = alloc_h((size_t)NBATCH * HEXP);
    unsigned short* PPb = alloc_h((size_t)NBATCH * NCLS * RNK);
    unsigned short* W6T  = alloc_h((size_t)DDIM * DDIM);
    unsigned short* W7T  = alloc_h((size_t)DDIM * DDIM);
    unsigned short* WpT  = alloc_h((size_t)DDIM * DDIM);
    unsigned short* inWT = alloc_h((size_t)HIDD * DDIM);
    unsigned short* f1WT = alloc_h((size_t)NBLK * HIDD * HEXP);
    unsigned short* f2WT = alloc_h((size_t)NBLK * HIDD * HEXP);
    unsigned short* oWT  = alloc_h((size_t)NCLS * RNK * HIDD);
    unsigned short* geneB= alloc_h((size_t)NGPAD * RNK);       // padded rows

    const int* esrc = eidx;
    const int* edst = eidx + N_EDGES;
    dim3 blk(256);

    // ---- weight prep (+cnt/mark zero tail) and init/gene/mark ----
    prep_all_kernel<<<dim3(PREP_TILES + 2 * ZERO_BLKS), blk, 0, stream>>>(
        W6, W7, Wp, inW, f1W, f2W, oW, W6T, W7T, WpT, inWT, f1WT, f2WT, oWT, cnt, mark);
    const int node4 = N_NODES * DDIM / 4;
    const int gene4 = NGENE * RNK / 4;
    init_and_gene_kernel<<<dim3((node4 + gene4 + NBATCH + 255) / 256), blk, 0, stream>>>(
        (const float4*)fro, (float4*)X, (ushort4*)Xb, node4, gene, geneB, gene4, idxs, mark);

    // ---- CSR build (by dst) ----
    hist_kernel<<<dim3(N_EDGES / 256), blk, 0, stream>>>(edst, cnt);
    scan_kernel<<<dim3(1), blk, 0, stream>>>(cnt, off, cur);
    fill_kernel<<<dim3(N_EDGES / 256), blk, 0, stream>>>(esrc, edst, ew, cur, ssrc, sw);

    // ---- GNN tail ----
    dim3 gnn_grid(DDIM / 128, N_PAD / 128);
    gemm_mfma<128, 128, 0, true><<<gnn_grid, blk, 0, stream>>>(
        Xb, DDIM, W6T, DDIM, Yb, DDIM, nullptr, N_NODES, DDIM, DDIM);
    agg_update_kernel<true><<<dim3(N_NODES / 4), blk, 0, stream>>>(
        Yb, off, ssrc, sw, b6, X, Xb, nullptr);
    gemm_mfma<128, 128, 0, true><<<gnn_grid, blk, 0, stream>>>(
        Xb, DDIM, W7T, DDIM, Yb, DDIM, nullptr, N_NODES, DDIM, DDIM);
    // layer 2: X is only read via gather -> update only gathered (marked) nodes
    agg_update_kernel<false><<<dim3(N_NODES / 4), blk, 0, stream>>>(
        Yb, off, ssrc, sw, b7, X, nullptr, mark);

    // project only gathered rows: Ag = bf16(X[clip(idx)]), Zp = Ag @ Wp + bp
    gather_cvt_kernel<<<dim3(NBATCH / 4), blk, 0, stream>>>(X, idxs, Ag);
    gemm_mfma<64, 128, 0, false><<<dim3(DDIM / 128, NBATCH / 64), blk, 0, stream>>>(
        Ag, DDIM, WpT, DDIM, Zp, DDIM, bp, NBATCH, DDIM, DDIM);
    // oov-select + input LN fused (wave-per-row)
    ln_oov_kernel<<<dim3(NBATCH / 4), blk, 0, stream>>>(Zp, idxs, oov, in_g, in_b, HN256);

    // ---- head ----
    // inW: BM=32 -> 512 blocks (2/CU occupancy fix)
    gemm_mfma<32, 128, 0, false><<<dim3(HIDD / 128, NBATCH / 32), blk, 0, stream>>>(
        HN256, DDIM, inWT, DDIM, H, HIDD, inb, NBATCH, HIDD, DDIM);
    for (int i = 0; i < NBLK; ++i) {
        ln512_kernel<<<dim3(NBATCH / 4), blk, 0, stream>>>(H, bg + (size_t)i * HIDD,
                                                           bb + (size_t)i * HIDD, HN512);
        gemm_mfma<128, 128, 2, true><<<dim3(HEXP / 128, NBATCH / 128), blk, 0, stream>>>(
            HN512, HIDD, f1WT + (size_t)i * HEXP * HIDD, HIDD, Tb, HEXP,
            f1b + (size_t)i * HEXP, NBATCH, HEXP, HIDD);
        // fc2: BM=32 -> 512 blocks (2/CU occupancy fix)
        gemm_mfma<32, 128, 3, false><<<dim3(HIDD / 128, NBATCH / 32), blk, 0, stream>>>(
            Tb, HEXP, f2WT + (size_t)i * HIDD * HEXP, HEXP, H, HIDD,
            f2b + (size_t)i * HIDD, NBATCH, HIDD, HEXP);
    }
    ln512_kernel<<<dim3(NBATCH / 4), blk, 0, stream>>>(H, og, ob, HN512);
    gemm_mfma<128, 128, 0, true><<<dim3(NCLS * RNK / 128, NBATCH / 128), blk, 0, stream>>>(
        HN512, HIDD, oWT, HIDD, PPb, NCLS * RNK, obia, NBATCH, NCLS * RNK, HIDD);

    // ---- bilinear gene head: 256x256 8-wave fine-interleaved kernel ----
    gemm_gene<<<dim3(NGPAD / 256, NBATCH * NCLS / 256), dim3(512), 0, stream>>>(
        PPb, RNK, geneB, RNK, out, NGENE, NBATCH * NCLS, NGENE, RNK);
}

// Round 16
// 785.771 us; speedup vs baseline: 1.0517x; 1.0019x over previous
//
#include <hip/hip_runtime.h>
#include <cstdint>
#include <cstddef>

#define N_NODES 20000
#define N_PAD   20096   // 157*128
#define N_EDGES 640000
#define DDIM    256
#define HIDD    512
#define NBLK    6
#define HEXP    2048    // HID*EXP
#define NCLS    3
#define RNK     512
#define NGENE   6640
#define NGPAD   6656    // 26*256
#define NBATCH  4096

typedef __attribute__((ext_vector_type(8))) short short8;
typedef __attribute__((ext_vector_type(4))) float f32x4;

__device__ __forceinline__ float gelu_tanh(float x) {
    float x3 = x * x * x;
    return 0.5f * x * (1.f + tanhf(0.7978845608028654f * (x + 0.044715f * x3)));
}

// f32 -> bf16 RNE bit pattern
__device__ __forceinline__ unsigned short f2bf(float f) {
    unsigned u = __float_as_uint(f);
    unsigned r = (u + 0x7FFFu + ((u >> 16) & 1u)) >> 16;
    return (unsigned short)r;
}

__device__ __forceinline__ float bf2f(unsigned short h) {
    return __uint_as_float((unsigned)h << 16);
}

// async global->LDS, 16B per lane. LDS dest is wave-uniform base + lane*16.
__device__ __forceinline__ void gload16(const unsigned short* g, short* l) {
    __builtin_amdgcn_global_load_lds(
        (const __attribute__((address_space(1))) void*)g,
        (__attribute__((address_space(3))) void*)l, 16, 0, 0);
}

// counted vmcnt wait (immediate must be literal)
template <int N>
__device__ __forceinline__ void waitvm() {
    if constexpr (N == 0)      asm volatile("s_waitcnt vmcnt(0)" ::: "memory");
    else if constexpr (N == 5) asm volatile("s_waitcnt vmcnt(5)" ::: "memory");
    else if constexpr (N == 6) asm volatile("s_waitcnt vmcnt(6)" ::: "memory");
    else if constexpr (N == 8) asm volatile("s_waitcnt vmcnt(8)" ::: "memory");
    else if constexpr (N == 12) asm volatile("s_waitcnt vmcnt(12)" ::: "memory");
    else static_assert(N == 0, "unsupported vmcnt");
}

// block remap: XCD-bijective chunking (m204) + 16-row supertiles for L2 reuse.
__device__ __forceinline__ void remap_block(int& bx, int& by) {
    const int NBX = gridDim.x, NBY = gridDim.y;
    const int nwg = NBX * NBY;
    int orig = blockIdx.y * NBX + blockIdx.x;
    int q = nwg >> 3, r = nwg & 7;
    int xcd = orig & 7, lid = orig >> 3;
    int w = (xcd < r ? xcd * (q + 1) : r * (q + 1) + (xcd - r) * q) + lid;
    int G = NBY < 16 ? NBY : 16;
    int per = G * NBX;
    int full = NBY / G;
    if (w < full * per) {
        int g = w / per, rem = w % per;
        bx = rem / G;
        by = g * G + (rem % G);
    } else {
        int w2 = w - full * per;
        int tG = NBY - full * G;
        bx = w2 / tG;
        by = full * G + w2 % tG;
    }
}

// ---------------- utility kernels ----------------
// merged: initX + gene f32->bf16 convert + gathered-node marking + CSR histogram
// (cnt/mark are zeroed by the PRECEDING prep_all launch -> stream-ordered safe)
__global__ __launch_bounds__(256) void init_and_gene_kernel(const float4* __restrict__ fro,
                                                            float4* __restrict__ X,
                                                            ushort4* __restrict__ Xb, int n4x,
                                                            const float* __restrict__ gene,
                                                            unsigned short* __restrict__ geneB,
                                                            int n4g,
                                                            const int* __restrict__ idxs,
                                                            int* __restrict__ mark,
                                                            const int* __restrict__ edst,
                                                            int* __restrict__ cnt) {
    int i = blockIdx.x * 256 + threadIdx.x;
    if (i < n4x) {
        float4 v = fro[i];
        X[i] = v;
        ushort4 h;
        h.x = f2bf(v.x); h.y = f2bf(v.y); h.z = f2bf(v.z); h.w = f2bf(v.w);
        Xb[i] = h;
    } else if (i < n4x + n4g) {
        int j = i - n4x;
        float4 v = ((const float4*)gene)[j];
        ushort4 o;
        o.x = f2bf(v.x); o.y = f2bf(v.y); o.z = f2bf(v.z); o.w = f2bf(v.w);
        ((ushort4*)geneB)[j] = o;
    } else if (i < n4x + n4g + NBATCH) {
        int b = i - n4x - n4g;
        int id = idxs[b];
        mark[id < 0 ? 0 : id] = 1;   // benign race: all write 1
    } else {
        int e = i - n4x - n4g - NBATCH;
        if (e < N_EDGES) atomicAdd(&cnt[edst[e]], 1);
    }
}

// ---------------- fused weight prep (+ cnt/mark zeroing tail blocks) ----------------
#define PREP_TILES 13376
#define ZERO_BLKS  ((N_NODES + 255) / 256)   // 79
__global__ __launch_bounds__(256) void prep_all_kernel(
        const float* W6, const float* W7, const float* Wp, const float* inW,
        const float* f1W, const float* f2W, const float* oW,
        unsigned short* W6T, unsigned short* W7T, unsigned short* WpT, unsigned short* inWT,
        unsigned short* f1WT, unsigned short* f2WT, unsigned short* oWT,
        int* cnt, int* mark) {
    int id = blockIdx.x;
    if (id >= PREP_TILES) {           // tail blocks: zero CSR histogram + mark flags
        int z = id - PREP_TILES;
        if (z < ZERO_BLKS) {
            int i = z * 256 + threadIdx.x;
            if (i < N_NODES) cnt[i] = 0;
        } else {
            int i = (z - ZERO_BLKS) * 256 + threadIdx.x;
            if (i < N_NODES) mark[i] = 0;
        }
        return;
    }
    const float* in; unsigned short* out; int R, C, nx, local;
    if (id < 192) {            // W6/W7/Wp
        int m = id / 64; local = id % 64;
        in = m == 0 ? W6 : (m == 1 ? W7 : Wp);
        out = m == 0 ? W6T : (m == 1 ? W7T : WpT);
        R = DDIM; C = DDIM; nx = 8;
    } else if (id < 320) {     // inW 256x512
        local = id - 192; in = inW; out = inWT; R = DDIM; C = HIDD; nx = 16;
    } else if (id < 6464) {    // f1W 6 x 512x2048
        local = id - 320; int layer = local / 1024; local %= 1024;
        in = f1W + (size_t)layer * HIDD * HEXP; out = f1WT + (size_t)layer * HEXP * HIDD;
        R = HIDD; C = HEXP; nx = 64;
    } else if (id < 12608) {   // f2W 6 x 2048x512
        local = id - 6464; int layer = local / 1024; local %= 1024;
        in = f2W + (size_t)layer * HEXP * HIDD; out = f2WT + (size_t)layer * HIDD * HEXP;
        R = HEXP; C = HIDD; nx = 16;
    } else {                   // oW 512x1536
        local = id - 12608; in = oW; out = oWT; R = HIDD; C = NCLS * RNK; nx = 48;
    }
    int bx = local % nx, by = local / nx;
    __shared__ float tile[32][33];
    int c0 = bx * 32, r0 = by * 32;
    int tx = threadIdx.x & 31, ty = threadIdx.x >> 5;
#pragma unroll
    for (int i = 0; i < 4; ++i) {
        int r = r0 + ty + i * 8, c = c0 + tx;
        tile[ty + i * 8][tx] = (r < R && c < C) ? in[(size_t)r * C + c] : 0.f;
    }
    __syncthreads();
#pragma unroll
    for (int i = 0; i < 4; ++i) {
        int c = c0 + ty + i * 8, r = r0 + tx;
        if (c < C && r < R) out[(size_t)c * R + r] = f2bf(tile[tx][ty + i * 8]);
    }
}

// ---------------- CSR build ----------------
__global__ __launch_bounds__(256) void scan_kernel(const int* __restrict__ cnt,
                                                   int* __restrict__ off,
                                                   int* __restrict__ cur) {
    __shared__ int part[256];
    const int CH = (N_NODES + 255) / 256;
    int t = threadIdx.x;
    int base = t * CH;
    int s = 0;
    for (int j = 0; j < CH; ++j) {
        int i = base + j;
        if (i < N_NODES) s += cnt[i];
    }
    part[t] = s;
    __syncthreads();
    for (int d = 1; d < 256; d <<= 1) {
        int v = (t >= d) ? part[t - d] : 0;
        __syncthreads();
        part[t] += v;
        __syncthreads();
    }
    int run = part[t] - s;
    for (int j = 0; j < CH; ++j) {
        int i = base + j;
        if (i < N_NODES) {
            off[i] = run; cur[i] = run;
            run += cnt[i];
        }
    }
    if (t == 255) off[N_NODES] = run;
}

__global__ __launch_bounds__(256) void fill_kernel(const int* __restrict__ src,
                                                   const int* __restrict__ dst,
                                                   const float* __restrict__ ew,
                                                   int* __restrict__ cur,
                                                   int* __restrict__ ssrc,
                                                   float* __restrict__ sw) {
    int e = blockIdx.x * 256 + threadIdx.x;
    if (e >= N_EDGES) return;
    int slot = atomicAdd(&cur[dst[e]], 1);
    ssrc[slot] = src[e];
    sw[slot]   = ew[e];
}

// fused aggregation + update, one wave per node, bf16 Y rows, 8-deep unrolled ILP.
// mark != nullptr: only process marked nodes (layer-2: only gathered nodes are read)
template <bool WB>
__global__ __launch_bounds__(256) void agg_update_kernel(const unsigned short* __restrict__ Y,
                                                         const int* __restrict__ off,
                                                         const int* __restrict__ ssrc,
                                                         const float* __restrict__ sw,
                                                         const float* __restrict__ bias,
                                                         float* __restrict__ X,
                                                         unsigned short* __restrict__ Xb,
                                                         const int* __restrict__ mark) {
    int node = blockIdx.x * 4 + (threadIdx.x >> 6);
    int lane = threadIdx.x & 63;
    if (mark != nullptr && mark[node] == 0) return;   // wave-uniform
    int b = off[node], e = off[node + 1];
    const ushort4* Yv = (const ushort4*)Y;
    float4 acc = make_float4(0.f, 0.f, 0.f, 0.f);
    int j = b;
    for (; j + 7 < e; j += 8) {
        int s[8];
        float w[8];
        ushort4 v[8];
#pragma unroll
        for (int k = 0; k < 8; ++k) { s[k] = ssrc[j + k]; w[k] = sw[j + k]; }
#pragma unroll
        for (int k = 0; k < 8; ++k) v[k] = Yv[(size_t)s[k] * 64 + lane];
#pragma unroll
        for (int k = 0; k < 8; ++k) {
            acc.x += bf2f(v[k].x) * w[k];
            acc.y += bf2f(v[k].y) * w[k];
            acc.z += bf2f(v[k].z) * w[k];
            acc.w += bf2f(v[k].w) * w[k];
        }
    }
    for (; j < e; ++j) {
        int s = ssrc[j];
        float w = sw[j];
        ushort4 v = Yv[(size_t)s * 64 + lane];
        acc.x += bf2f(v.x) * w; acc.y += bf2f(v.y) * w;
        acc.z += bf2f(v.z) * w; acc.w += bf2f(v.w) * w;
    }
    float4 bv = ((const float4*)bias)[lane];
    size_t o = (size_t)node * 64 + lane;
    float4 x = ((float4*)X)[o];
    x.x += fmaxf(acc.x + bv.x, 0.f);
    x.y += fmaxf(acc.y + bv.y, 0.f);
    x.z += fmaxf(acc.z + bv.z, 0.f);
    x.w += fmaxf(acc.w + bv.w, 0.f);
    ((float4*)X)[o] = x;
    if (WB) {
        ushort4 h;
        h.x = f2bf(x.x); h.y = f2bf(x.y); h.z = f2bf(x.z); h.w = f2bf(x.w);
        ((ushort4*)Xb)[o] = h;
    }
}

// gather rows of X (f32) at clip(idx,0) -> bf16 [NBATCH][DDIM]; one wave per row
__global__ __launch_bounds__(256) void gather_cvt_kernel(const float* __restrict__ X,
                                                         const int* __restrict__ idxs,
                                                         unsigned short* __restrict__ Ag) {
    int b = blockIdx.x * 4 + (threadIdx.x >> 6);
    int lane = threadIdx.x & 63;
    int id = idxs[b];
    if (id < 0) id = 0;
    float4 v = *(const float4*)(X + (size_t)id * DDIM + lane * 4);
    ushort4 o;
    o.x = f2bf(v.x); o.y = f2bf(v.y); o.z = f2bf(v.z); o.w = f2bf(v.w);
    *(ushort4*)(Ag + (size_t)b * DDIM + lane * 4) = o;
}

// LN over 256 cols with OOV substitution, one WAVE per row (4 cols/lane), bf16 out
__global__ __launch_bounds__(256) void ln_oov_kernel(const float* __restrict__ Z,
                                                     const int* __restrict__ idxs,
                                                     const float* __restrict__ oov,
                                                     const float* __restrict__ g,
                                                     const float* __restrict__ bb,
                                                     unsigned short* __restrict__ Y) {
    int row = blockIdx.x * 4 + (threadIdx.x >> 6);
    int lane = threadIdx.x & 63;
    int id = idxs[row];
    float4 v = (id >= 0) ? *(const float4*)(Z + (size_t)row * DDIM + lane * 4)
                         : *(const float4*)(oov + lane * 4);
    float sum = v.x + v.y + v.z + v.w;
    float sq  = v.x * v.x + v.y * v.y + v.z * v.z + v.w * v.w;
#pragma unroll
    for (int m = 1; m < 64; m <<= 1) {
        sum += __shfl_xor(sum, m);
        sq  += __shfl_xor(sq, m);
    }
    float mu  = sum * (1.f / DDIM);
    float var = sq * (1.f / DDIM) - mu * mu;
    float r   = rsqrtf(var + 1e-5f);
    float4 gv = *(const float4*)(g + lane * 4);
    float4 bv = *(const float4*)(bb + lane * 4);
    ushort4 o;
    o.x = f2bf((v.x - mu) * r * gv.x + bv.x);
    o.y = f2bf((v.y - mu) * r * gv.y + bv.y);
    o.z = f2bf((v.z - mu) * r * gv.z + bv.z);
    o.w = f2bf((v.w - mu) * r * gv.w + bv.w);
    *(ushort4*)(Y + (size_t)row * DDIM + lane * 4) = o;
}

// LN over 512 cols, one WAVE per row (8 cols/lane), f32 in -> bf16 out
__global__ __launch_bounds__(256) void ln512_kernel(const float* __restrict__ X,
                                                    const float* __restrict__ g,
                                                    const float* __restrict__ bb,
                                                    unsigned short* __restrict__ Y) {
    int row = blockIdx.x * 4 + (threadIdx.x >> 6);
    int lane = threadIdx.x & 63;
    const float* x = X + (size_t)row * HIDD + lane * 8;
    float4 a = *(const float4*)x;
    float4 b = *(const float4*)(x + 4);
    float sum = a.x + a.y + a.z + a.w + b.x + b.y + b.z + b.w;
    float sq  = a.x * a.x + a.y * a.y + a.z * a.z + a.w * a.w
              + b.x * b.x + b.y * b.y + b.z * b.z + b.w * b.w;
#pragma unroll
    for (int m = 1; m < 64; m <<= 1) {
        sum += __shfl_xor(sum, m);
        sq  += __shfl_xor(sq, m);
    }
    float mu  = sum * (1.f / HIDD);
    float var = sq * (1.f / HIDD) - mu * mu;
    float r   = rsqrtf(var + 1e-5f);
    const float* gp = g + lane * 8;
    const float* bp = bb + lane * 8;
    float4 g0 = *(const float4*)gp, g1 = *(const float4*)(gp + 4);
    float4 b0 = *(const float4*)bp, b1 = *(const float4*)(bp + 4);
    ushort4 o0, o1;
    o0.x = f2bf((a.x - mu) * r * g0.x + b0.x);
    o0.y = f2bf((a.y - mu) * r * g0.y + b0.y);
    o0.z = f2bf((a.z - mu) * r * g0.z + b0.z);
    o0.w = f2bf((a.w - mu) * r * g0.w + b0.w);
    o1.x = f2bf((b.x - mu) * r * g1.x + b1.x);
    o1.y = f2bf((b.y - mu) * r * g1.y + b1.y);
    o1.z = f2bf((b.z - mu) * r * g1.z + b1.z);
    o1.w = f2bf((b.w - mu) * r * g1.w + b1.w);
    unsigned short* y = Y + (size_t)row * HIDD + lane * 8;
    *(ushort4*)y       = o0;
    *(ushort4*)(y + 4) = o1;
}

// ---------------- bf16 MFMA GEMM (dbuf + counted vmcnt pipeline) ----------------
// R6/R12-proven form: 256 threads = 4 waves (2x2), wave tile (BM/2)x(BN/2),
// BK=64, double-buffered LDS, counted vmcnt (never 0 mid-loop) + raw s_barrier.
// BM=32 variant (MF=1) doubles blocks/CU for N<=512 shapes (occupancy fix).
// EPI: 0 = +bias ; 2 = gelu(+bias) ; 3 = C(f32) += (+bias).  BOUT: bf16 store.
// NTS: non-temporal C store.
template <int BM, int BN, int EPI, bool BOUT, bool NTS = false>
__global__ __launch_bounds__(256) void gemm_mfma(const unsigned short* __restrict__ A, int lda,
                                                 const unsigned short* __restrict__ BT, int ldb,
                                                 void* __restrict__ Cv, int ldc,
                                                 const float* __restrict__ bias,
                                                 int M, int N, int K) {
    constexpr int WM = BM / 2, WN = BN / 2;
    constexpr int MF = WM / 16, NF = WN / 16;
    constexpr int ROWS  = BM + BN;
    constexpr int NCALL = ROWS / 32;       // gload16 per wave per k-tile
    __shared__ __align__(16) short lds[2 * ROWS * 64];

    int bx, by;
    remap_block(bx, by);

    const int tid  = threadIdx.x;
    const int lane = tid & 63;
    const int wid  = tid >> 6;
    const int wr   = (wid >> 1) * WM;
    const int wc   = (wid & 1) * WN;
    const int fq   = lane >> 4;
    const int fr   = lane & 15;
    const int m0 = by * BM, n0 = bx * BN;

    const int srow  = lane >> 3;                   // row within 8-row chunk
    const int tslot = ((lane & 7) ^ srow) * 8;     // pre-swizzled global slot (elems)

    f32x4 acc[MF][NF] = {};

    auto stage = [&](int k0, int buf) {
        short* dst = lds + buf * (ROWS * 64);
#pragma unroll
        for (int c = 0; c < NCALL; ++c) {
            int r = c * 32 + wid * 8 + srow;       // concatenated row (A then B)
            const unsigned short* src =
                (r < BM) ? (A  + (size_t)(m0 + r) * lda      + k0 + tslot)
                         : (BT + (size_t)(n0 + r - BM) * ldb + k0 + tslot);
            gload16(src, dst + (c * 32 + wid * 8) * 64);
        }
    };

    const int nsteps = K >> 6;
    stage(0, 0);
    for (int t = 0; t < nsteps; ++t) {
        const int buf = t & 1;
        if (t + 1 < nsteps) {
            stage((t + 1) << 6, buf ^ 1);
            waitvm<NCALL>();                       // tile t done; t+1 stays in flight
        } else {
            waitvm<0>();
        }
        __builtin_amdgcn_sched_barrier(0);
        __builtin_amdgcn_s_barrier();
        __builtin_amdgcn_sched_barrier(0);

        const short* L = lds + buf * (ROWS * 64);
#pragma unroll
        for (int kk = 0; kk < 2; ++kk) {
            short8 af[MF], bf[NF];
#pragma unroll
            for (int m = 0; m < MF; ++m) {
                int row = wr + m * 16 + fr;
                af[m] = *(const short8*)(L + row * 64 + ((kk * 4 + fq) ^ (row & 7)) * 8);
            }
#pragma unroll
            for (int n = 0; n < NF; ++n) {
                int row = BM + wc + n * 16 + fr;
                bf[n] = *(const short8*)(L + row * 64 + ((kk * 4 + fq) ^ (row & 7)) * 8);
            }
#pragma unroll
            for (int m = 0; m < MF; ++m)
#pragma unroll
                for (int n = 0; n < NF; ++n)
                    acc[m][n] = __builtin_amdgcn_mfma_f32_16x16x32_bf16(af[m], bf[n], acc[m][n], 0, 0, 0);
        }
        __builtin_amdgcn_sched_barrier(0);
        __builtin_amdgcn_s_barrier();
        __builtin_amdgcn_sched_barrier(0);
    }

    float* Cf = (float*)Cv;
    unsigned short* Cb = (unsigned short*)Cv;
#pragma unroll
    for (int n = 0; n < NF; ++n) {
        int col = n0 + wc + n * 16 + fr;
        if (col >= N) continue;
        float bv = bias ? bias[col] : 0.f;
#pragma unroll
        for (int m = 0; m < MF; ++m) {
#pragma unroll
            for (int r = 0; r < 4; ++r) {
                int row = m0 + wr + m * 16 + fq * 4 + r;
                if (row >= M) continue;
                float v = acc[m][n][r] + bv;
                if (EPI == 2) v = gelu_tanh(v);
                size_t o = (size_t)row * ldc + col;
                if (EPI == 3) v += Cf[o];
                if (BOUT)      Cb[o] = f2bf(v);
                else if (NTS)  __builtin_nontemporal_store(v, &Cf[o]);
                else           Cf[o] = v;
            }
        }
    }
}

// ---------------- 256x256 8-wave gene GEMM (m201-style fine interleave) --------
// (R12 version — unchanged)
__global__ __launch_bounds__(512, 2) void gemm_gene(const unsigned short* __restrict__ A, int lda,
                                                    const unsigned short* __restrict__ BT, int ldb,
                                                    float* __restrict__ C, int ldc,
                                                    int M, int N, int K) {
    __shared__ __align__(16) short lds[2 * 512 * 64];   // [buf][A 256 rows | B 256 rows][64]

    int bx, by;
    remap_block(bx, by);

    const int tid  = threadIdx.x;
    const int lane = tid & 63;
    const int wid  = tid >> 6;          // 0..7
    const int wm   = wid >> 2;          // 0..1 -> row offset wm*128
    const int wn   = wid & 3;           // 0..3 -> col offset wn*64
    const int fq   = lane >> 4;
    const int fr   = lane & 15;
    const int m0 = by * 256, n0 = bx * 256;

    const int tslot = ((tid & 7) ^ ((tid >> 3) & 7)) * 8;   // pre-swizzled global slot

    f32x4 acc[8][4] = {};

    auto stage = [&](int k0, int buf) {
        short* dst = lds + buf * (512 * 64);
#pragma unroll
        for (int u = 0; u < 8; ++u) {
            int rw = u * 64 + wid * 8;              // wave-uniform base row
            int r  = rw + (lane >> 3);              // this lane's concat row
            const unsigned short* src =
                (r < 256) ? (A  + (size_t)(m0 + r) * lda       + k0 + tslot)
                          : (BT + (size_t)(n0 + r - 256) * ldb + k0 + tslot);
            gload16(src, dst + rw * 64);
        }
    };

    const int nsteps = K >> 6;
    stage(0, 0);
    for (int t = 0; t < nsteps; ++t) {
        const int buf = t & 1;
        if (t + 1 < nsteps) {
            stage((t + 1) << 6, buf ^ 1);
            waitvm<8>();                            // tile t done; t+1's 8 in flight
        } else {
            waitvm<0>();
        }
        __builtin_amdgcn_sched_barrier(0);
        __builtin_amdgcn_s_barrier();
        __builtin_amdgcn_sched_barrier(0);

        const short* L = lds + buf * (512 * 64);
#pragma unroll
        for (int q = 0; q < 4; ++q) {               // quadrant phases, barrier-fenced
            const int mb = (q >> 1) * 4, nb = (q & 1) * 2;
            short8 af[4][2], bf[2][2];
#pragma unroll
            for (int m = 0; m < 4; ++m) {
                int row = wm * 128 + (mb + m) * 16 + fr;
#pragma unroll
                for (int kk = 0; kk < 2; ++kk)
                    af[m][kk] = *(const short8*)(L + row * 64 + ((kk * 4 + fq) ^ (row & 7)) * 8);
            }
#pragma unroll
            for (int n = 0; n < 2; ++n) {
                int row = 256 + wn * 64 + (nb + n) * 16 + fr;
#pragma unroll
                for (int kk = 0; kk < 2; ++kk)
                    bf[n][kk] = *(const short8*)(L + row * 64 + ((kk * 4 + fq) ^ (row & 7)) * 8);
            }
            __builtin_amdgcn_sched_barrier(0);
            __builtin_amdgcn_s_barrier();           // cluster issue phase
            asm volatile("s_waitcnt lgkmcnt(0)" ::: "memory");
            __builtin_amdgcn_sched_barrier(0);      // rule #18: pin MFMA below the wait
            __builtin_amdgcn_s_setprio(1);
#pragma unroll
            for (int kk = 0; kk < 2; ++kk)
#pragma unroll
                for (int m = 0; m < 4; ++m)
#pragma unroll
                    for (int n = 0; n < 2; ++n)
                        acc[mb + m][nb + n] = __builtin_amdgcn_mfma_f32_16x16x32_bf16(
                            af[m][kk], bf[n][kk], acc[mb + m][nb + n], 0, 0, 0);
            __builtin_amdgcn_s_setprio(0);
            __builtin_amdgcn_sched_barrier(0);
            __builtin_amdgcn_s_barrier();           // end of MFMA phase
            __builtin_amdgcn_sched_barrier(0);
        }
    }

#pragma unroll
    for (int n = 0; n < 4; ++n) {
        int col = n0 + wn * 64 + n * 16 + fr;
        if (col >= N) continue;
#pragma unroll
        for (int m = 0; m < 8; ++m) {
#pragma unroll
            for (int r = 0; r < 4; ++r) {
                int row = m0 + wm * 128 + m * 16 + fq * 4 + r;
                if (row >= M) continue;
                __builtin_nontemporal_store(acc[m][n][r], &C[(size_t)row * ldc + col]);
            }
        }
    }
}

// ---------------- launcher ----------------
static inline char* align256(char* p) {
    return (char*)(((uintptr_t)p + 255) & ~(uintptr_t)255);
}

extern "C" void kernel_launch(void* const* d_in, const int* in_sizes, int n_in,
                              void* d_out, int out_size, void* d_ws, size_t ws_size,
                              hipStream_t stream) {
    const int*   idxs = (const int*)d_in[0];
    const float* fro  = (const float*)d_in[1];
    const int*   eidx = (const int*)d_in[2];
    const float* ew   = (const float*)d_in[3];
    const float* W6   = (const float*)d_in[4];
    const float* b6   = (const float*)d_in[5];
    const float* W7   = (const float*)d_in[6];
    const float* b7   = (const float*)d_in[7];
    const float* Wp   = (const float*)d_in[8];
    const float* bp   = (const float*)d_in[9];
    const float* oov  = (const float*)d_in[10];
    const float* in_g = (const float*)d_in[11];
    const float* in_b = (const float*)d_in[12];
    const float* inW  = (const float*)d_in[13];
    const float* inb  = (const float*)d_in[14];
    const float* bg   = (const float*)d_in[15];
    const float* bb   = (const float*)d_in[16];
    const float* f1W  = (const float*)d_in[17];
    const float* f1b  = (const float*)d_in[18];
    const float* f2W  = (const float*)d_in[19];
    const float* f2b  = (const float*)d_in[20];
    const float* og   = (const float*)d_in[21];
    const float* ob   = (const float*)d_in[22];
    const float* oW   = (const float*)d_in[23];
    const float* obia = (const float*)d_in[24];
    const float* gene = (const float*)d_in[25];
    float* out = (float*)d_out;

    // ---- workspace carve-up ----
    char* p = (char*)d_ws;
    auto alloc_f = [&](size_t n) { float* r = (float*)p; p = align256(p + n * 4); return r; };
    auto alloc_i = [&](size_t n) { int*   r = (int*)p;   p = align256(p + n * 4); return r; };
    auto alloc_h = [&](size_t n) { unsigned short* r = (unsigned short*)p; p = align256(p + n * 2); return r; };

    float* X    = alloc_f((size_t)N_NODES * DDIM);
    unsigned short* Yb = alloc_h((size_t)N_NODES * DDIM);
    int*   cnt  = alloc_i(N_NODES);
    int*   mark = alloc_i(N_NODES);
    int*   off  = alloc_i(N_NODES + 1);
    int*   cur  = alloc_i(N_NODES);
    int*   ssrc = alloc_i(N_EDGES);
    float* sw   = alloc_f(N_EDGES);
    unsigned short* Xb  = alloc_h((size_t)N_PAD * DDIM);      // padded rows for gload_lds
    unsigned short* Ag  = alloc_h((size_t)NBATCH * DDIM);
    float* Zp   = alloc_f((size_t)NBATCH * DDIM);
    unsigned short* HN256 = alloc_h((size_t)NBATCH * DDIM);
    float* H    = alloc_f((size_t)NBATCH * HIDD);
    unsigned short* HN512 = alloc_h((size_t)NBATCH * HIDD);
    unsigned short* Tb  = alloc_h((size_t)NBATCH * HEXP);
    unsigned short* PPb = alloc_h((size_t)NBATCH * NCLS * RNK);
    unsigned short* W6T  = alloc_h((size_t)DDIM * DDIM);
    unsigned short* W7T  = alloc_h((size_t)DDIM * DDIM);
    unsigned short* WpT  = alloc_h((size_t)DDIM * DDIM);
    unsigned short* inWT = alloc_h((size_t)HIDD * DDIM);
    unsigned short* f1WT = alloc_h((size_t)NBLK * HIDD * HEXP);
    unsigned short* f2WT = alloc_h((size_t)NBLK * HIDD * HEXP);
    unsigned short* oWT  = alloc_h((size_t)NCLS * RNK * HIDD);
    unsigned short* geneB= alloc_h((size_t)NGPAD * RNK);       // padded rows

    const int* esrc = eidx;
    const int* edst = eidx + N_EDGES;
    dim3 blk(256);

    // ---- weight prep (+cnt/mark zero tail), then init/gene/mark/hist ----
    prep_all_kernel<<<dim3(PREP_TILES + 2 * ZERO_BLKS), blk, 0, stream>>>(
        W6, W7, Wp, inW, f1W, f2W, oW, W6T, W7T, WpT, inWT, f1WT, f2WT, oWT, cnt, mark);
    const int node4 = N_NODES * DDIM / 4;
    const int gene4 = NGENE * RNK / 4;
    init_and_gene_kernel<<<dim3((node4 + gene4 + NBATCH + N_EDGES + 255) / 256), blk, 0, stream>>>(
        (const float4*)fro, (float4*)X, (ushort4*)Xb, node4, gene, geneB, gene4,
        idxs, mark, edst, cnt);

    // ---- CSR build (by dst) ----
    scan_kernel<<<dim3(1), blk, 0, stream>>>(cnt, off, cur);
    fill_kernel<<<dim3(N_EDGES / 256), blk, 0, stream>>>(esrc, edst, ew, cur, ssrc, sw);

    // ---- GNN tail ----
    dim3 gnn_grid(DDIM / 128, N_PAD / 128);
    gemm_mfma<128, 128, 0, true><<<gnn_grid, blk, 0, stream>>>(
        Xb, DDIM, W6T, DDIM, Yb, DDIM, nullptr, N_NODES, DDIM, DDIM);
    agg_update_kernel<true><<<dim3(N_NODES / 4), blk, 0, stream>>>(
        Yb, off, ssrc, sw, b6, X, Xb, nullptr);
    gemm_mfma<128, 128, 0, true><<<gnn_grid, blk, 0, stream>>>(
        Xb, DDIM, W7T, DDIM, Yb, DDIM, nullptr, N_NODES, DDIM, DDIM);
    // layer 2: X is only read via gather -> update only gathered (marked) nodes
    agg_update_kernel<false><<<dim3(N_NODES / 4), blk, 0, stream>>>(
        Yb, off, ssrc, sw, b7, X, nullptr, mark);

    // project only gathered rows: Ag = bf16(X[clip(idx)]), Zp = Ag @ Wp + bp
    gather_cvt_kernel<<<dim3(NBATCH / 4), blk, 0, stream>>>(X, idxs, Ag);
    gemm_mfma<64, 128, 0, false><<<dim3(DDIM / 128, NBATCH / 64), blk, 0, stream>>>(
        Ag, DDIM, WpT, DDIM, Zp, DDIM, bp, NBATCH, DDIM, DDIM);
    // oov-select + input LN fused (wave-per-row)
    ln_oov_kernel<<<dim3(NBATCH / 4), blk, 0, stream>>>(Zp, idxs, oov, in_g, in_b, HN256);

    // ---- head ----
    // inW: BM=32 -> 512 blocks (2/CU occupancy fix)
    gemm_mfma<32, 128, 0, false><<<dim3(HIDD / 128, NBATCH / 32), blk, 0, stream>>>(
        HN256, DDIM, inWT, DDIM, H, HIDD, inb, NBATCH, HIDD, DDIM);
    for (int i = 0; i < NBLK; ++i) {
        ln512_kernel<<<dim3(NBATCH / 4), blk, 0, stream>>>(H, bg + (size_t)i * HIDD,
                                                           bb + (size_t)i * HIDD, HN512);
        gemm_mfma<128, 128, 2, true><<<dim3(HEXP / 128, NBATCH / 128), blk, 0, stream>>>(
            HN512, HIDD, f1WT + (size_t)i * HEXP * HIDD, HIDD, Tb, HEXP,
            f1b + (size_t)i * HEXP, NBATCH, HEXP, HIDD);
        // fc2: BM=32 -> 512 blocks (2/CU occupancy fix)
        gemm_mfma<32, 128, 3, false><<<dim3(HIDD / 128, NBATCH / 32), blk, 0, stream>>>(
            Tb, HEXP, f2WT + (size_t)i * HIDD * HEXP, HEXP, H, HIDD,
            f2b + (size_t)i * HIDD, NBATCH, HIDD, HEXP);
    }
    ln512_kernel<<<dim3(NBATCH / 4), blk, 0, stream>>>(H, og, ob, HN512);
    gemm_mfma<128, 128, 0, true><<<dim3(NCLS * RNK / 128, NBATCH / 128), blk, 0, stream>>>(
        HN512, HIDD, oWT, HIDD, PPb, NCLS * RNK, obia, NBATCH, NCLS * RNK, HIDD);

    // ---- bilinear gene head: 256x256 8-wave fine-interleaved kernel ----
    gemm_gene<<<dim3(NGPAD / 256, NBATCH * NCLS / 256), dim3(512), 0, stream>>>(
        PPb, RNK, geneB, RNK, out, NGENE, NBATCH * NCLS, NGENE, RNK);
}